// Round 7
// baseline (354.160 us; speedup 1.0000x reference)
//
#include <hip/hip_runtime.h>
#include <hip/hip_fp16.h>

// GCN 2-layer: N=200000, E=6400000, 14 -> 16(relu) -> 2.
// Round 19: placement-derived affinity (HW_REG_XCC_ID) instead of blockIdx
// parity. blockIdx->XCD mapping drifts as the scheduler backfills slots, so
// round-15/16's parity heuristics decayed mid-kernel:
//   - agg1 FETCH was 50MB/launch (phase regions evicted: XCDs ended up
//     touching BOTH phase regions). Now phase = f(XCC_ID) + per-phase atomic
//     work cursors (2-try grab provably covers all chunks; cursors zeroed in
//     k_init each replay). Each XCD gathers ONE 1.6MB region, drift-proof.
//   - binA WRITE was 41MB vs 25.6 logical. sub-segment = XCC_ID: appends to
//     a segment come only from blocks physically on that XCD -> partial
//     lines merge in its L2. Overflow path keeps correctness mapping-free.
// Pipeline: init -> binA -> sort(+dinv) -> prep -> agg1A -> agg1B -> mlp -> agg2.

constexpr int NN = 200000;
constexpr int NE = 6400000;
constexpr int IC = 14;
constexpr int HC = 16;
constexpr int OC = 2;

constexpr int NBK = 392;                   // buckets of 512 dst nodes
constexpr int NSUB = 8;                    // sub-segments per bucket (= XCD id)
constexpr int SCAP = 2816;                 // per (sub,bucket) cap: mean 2058 + 16.7 sigma
constexpr int NSEG = NSUB * NBK;           // 3136 segments
constexpr int CCAP = NSUB * SCAP;          // 22528 csr per-bucket capacity
constexpr int SPT = (SCAP + 1023) / 1024;  // 3 reg slots per (thread, segment)
constexpr int TILE = 5120;                 // edges per binA tile
constexpr int BTH = 512;                   // binA threads
constexpr int IPT = TILE / BTH;            // 10
constexpr int IPT2 = IPT / 2;              // 5 pair-loads per thread
constexpr int NTILE = NE / TILE;           // 1250
constexpr int OVFCAP = 65536;
constexpr int NB = (NN + 255) / 256;       // 782
constexpr int NAGG = NN / 64;              // 3125 chunks per phase
constexpr int GSTR = 16;                   // gcur stride: 1 counter per 64B line

typedef unsigned long long ull;
typedef float f4v __attribute__((ext_vector_type(4)));

__device__ __forceinline__ int phase_of(unsigned src) {
    return src >= 100000u ? (src >= 150000u ? 3 : 2) : (src >= 50000u ? 1 : 0);
}

// Physical XCD id (0..7). Affinity heuristic only -- correctness never
// depends on the value (G16): binA has the overflow path, agg1 cursors
// guarantee coverage for any value distribution.
__device__ __forceinline__ int xcc_id() {
    int x;
    asm volatile("s_getreg_b32 %0, hwreg(HW_REG_XCC_ID)" : "=s"(x));
    return x & 7;
}

// init gcur (padded) + ovf counter + agg1 cursors + dtype flag
__global__ void k_init(int* __restrict__ gcur, const void* __restrict__ ei,
                       int* __restrict__ flag) {
    int i = blockIdx.x * blockDim.x + threadIdx.x;
    if (i < NSEG) gcur[i * GSTR] = i * SCAP;
    else if (i <= NSEG + 4) gcur[i * GSTR] = 0;  // ovf counter + 4 cursors
    if (i == 500) {  // one thread sniffs edge dtype
        const ull* p = (const ull*)ei;
        ull acc = 0ULL;
        for (int k = 0; k < 64; ++k) acc |= (p[k] >> 32);
        *flag = (acc == 0ULL) ? 1 : 0;  // 1 => int64 indices, 0 => int32
    }
}

// Bin edges by dst>>9 into per-(sub,bucket) global segments, sub = XCC_ID.
// Single pass over edges: dst+src pair-loaded, rank captured from the
// histogram atomic, both held in regs across the scan. LDS-staged for
// coalesced segment write-out.
__global__ __launch_bounds__(BTH, 8) void k_binA(const void* __restrict__ ei,
                                                 const int* __restrict__ flag,
                                                 int* __restrict__ gcur,
                                                 unsigned* __restrict__ binned,
                                                 ull* __restrict__ ovf) {
    __shared__ int hist[NBK];
    __shared__ int lofs[NBK];
    __shared__ int gofs[NBK];
    __shared__ int wsum[BTH / 64];
    __shared__ unsigned stage[TILE];

    int t = threadIdx.x;
    int fl = *flag;
    int tile0 = blockIdx.x * TILE;
    int segbase = xcc_id() * NBK;

    if (t < NBK) hist[t] = 0;
    __syncthreads();

    // single pass: dst+src pairs (16B loads), hist atomic rank capture.
    // pk = (dlow<<18)|src ; ra = (rank<<9)|bucket  (rank<5120 fits 13 bits)
    unsigned pk[IPT];
    unsigned ra[IPT];
#pragma unroll
    for (int k = 0; k < IPT2; ++k) {
        int e = tile0 + k * (2 * BTH) + 2 * t;
        int d0, d1, s0, s1;
        if (fl) {
            ulonglong2 dd = *(const ulonglong2*)((const long long*)ei + NE + e);
            ulonglong2 ss = *(const ulonglong2*)((const long long*)ei + e);
            d0 = (int)dd.x;
            d1 = (int)dd.y;
            s0 = (int)ss.x;
            s1 = (int)ss.y;
        } else {
            uint2 dd = *(const uint2*)((const int*)ei + NE + e);
            uint2 ss = *(const uint2*)((const int*)ei + e);
            d0 = (int)dd.x;
            d1 = (int)dd.y;
            s0 = (int)ss.x;
            s1 = (int)ss.y;
        }
        int b0 = d0 >> 9, b1 = d1 >> 9;
        int r0 = atomicAdd(&hist[b0], 1);
        int r1 = atomicAdd(&hist[b1], 1);
        pk[2 * k] = ((unsigned)(d0 & 511) << 18) | (unsigned)s0;
        pk[2 * k + 1] = ((unsigned)(d1 & 511) << 18) | (unsigned)s1;
        ra[2 * k] = ((unsigned)r0 << 9) | (unsigned)b0;
        ra[2 * k + 1] = ((unsigned)r1 << 9) | (unsigned)b1;
    }
    __syncthreads();

    // exclusive scan of 392 counts: pair-sum + 64-lane shfl scan + wave combine
    int h0 = 0, h1 = 0, p = 0;
    if (t < NBK / 2) {
        h0 = hist[2 * t];
        h1 = hist[2 * t + 1];
        p = h0 + h1;
    }
    int lane = t & 63;
    int w = t >> 6;
    int incl = p;
#pragma unroll
    for (int off = 1; off < 64; off <<= 1) {
        int v = __shfl_up(incl, off, 64);
        if (lane >= off) incl += v;
    }
    if (lane == 63) wsum[w] = incl;
    __syncthreads();
    int wbase = 0;
#pragma unroll
    for (int ww = 0; ww < BTH / 64; ++ww) wbase += (ww < w) ? wsum[ww] : 0;
    int ex = wbase + incl - p;
    if (t < NBK / 2) {
        lofs[2 * t] = ex;
        lofs[2 * t + 1] = ex + h0;
    }
    if (t < NBK) gofs[t] = atomicAdd(&gcur[(segbase + t) * GSTR], hist[t]);
    __syncthreads();

    // stage from regs at lofs[bucket] + rank (no global loads)
#pragma unroll
    for (int k = 0; k < IPT; ++k) {
        int b = (int)(ra[k] & 511u);
        int r = (int)(ra[k] >> 9);
        stage[lofs[b] + r] = pk[k];
    }
    __syncthreads();

    // coalesced write-out; bucket of slot i via seeded search on lofs
    for (int i = t; i < TILE; i += BTH) {
        int b = (i * 313) >> 12;  // ~ i / 13.06 (mean slots per bucket)
        if (b > NBK - 1) b = NBK - 1;
        while (b < NBK - 1 && lofs[b + 1] <= i) ++b;
        while (lofs[b] > i) --b;
        unsigned pack = stage[i];
        int seg = segbase + b;
        int dest = gofs[b] + (i - lofs[b]);
        if (dest < (seg + 1) * SCAP) {
            binned[dest] = pack;
        } else {  // overflow (never in practice)
            int op = atomicAdd(&gcur[NSEG * GSTR], 1);
            if (op < OVFCAP) {
                int d = (b << 9) | (int)(pack >> 18);
                int s = (int)(pack & 0x3FFFF);
                ovf[op] = ((ull)d << 32) | (unsigned)s;
            }
        }
    }
}

// bucket-local counting sort over 8 sub-segments, key = (dlow<<2)|phase(src).
// Single pass: rank captured from cnt atomic, (src, rank|key) in regs
// (static 8x3 slots); scatter into LDS stage at excl[key]+rank; coalesced
// uint4 write-out (every csr line written once -> no write amplification).
// Also computes dinv = rsqrt(degree+1) and packs 4x8-bit phase counts.
__global__ __launch_bounds__(1024, 4) void k_sort(const int* __restrict__ gcur,
                                                  const unsigned* __restrict__ binned,
                                                  const ull* __restrict__ ovf,
                                                  unsigned* __restrict__ csr,
                                                  float* __restrict__ dinv,
                                                  int* __restrict__ rsg,
                                                  unsigned* __restrict__ spl) {
    __shared__ int cnt[2048];
    __shared__ int excl[2048];
    __shared__ int wsum[16];
    __shared__ int nseg[NSUB];
    __shared__ unsigned stage[CCAP];      // 88KB sorted bucket staging
    int b = blockIdx.x;
    int t = threadIdx.x;
    cnt[t] = 0;
    cnt[t + 1024] = 0;
    if (t < NSUB) {
        int seg = t * NBK + b;
        nseg[t] = min(gcur[seg * GSTR] - seg * SCAP, SCAP);
    }
    __syncthreads();
    int nov = min(gcur[NSEG * GSTR], OVFCAP);

    // single pass: load + key + rank capture; held in regs (static indexing)
    unsigned srcv[NSUB * SPT];
    unsigned rkv[NSUB * SPT];
#pragma unroll
    for (int s = 0; s < NSUB; ++s) {
        int n = nseg[s];
        int sb = (s * NBK + b) * SCAP;
#pragma unroll
        for (int k = 0; k < SPT; ++k) {
            int i = k * 1024 + t;
            rkv[s * SPT + k] = 0xFFFFFFFFu;
            if (i < n) {
                unsigned pack = binned[sb + i];
                unsigned src = pack & 0x3FFFFu;
                int key = ((int)(pack >> 18) << 2) | phase_of(src);
                int r = atomicAdd(&cnt[key], 1);
                srcv[s * SPT + k] = src;
                rkv[s * SPT + k] = ((unsigned)r << 11) | (unsigned)key;
            }
        }
    }
    __syncthreads();

    // exclusive scan of 2048 counts: pair-sum + 1024-lane scan (16 waves)
    int h0 = cnt[2 * t];
    int h1 = cnt[2 * t + 1];
    int p = h0 + h1;
    int lane = t & 63;
    int w = t >> 6;
    int incl = p;
#pragma unroll
    for (int off = 1; off < 64; off <<= 1) {
        int v = __shfl_up(incl, off, 64);
        if (lane >= off) incl += v;
    }
    if (lane == 63) wsum[w] = incl;
    __syncthreads();
    int wbase = 0;
#pragma unroll
    for (int ww = 0; ww < 16; ++ww) wbase += (ww < w) ? wsum[ww] : 0;
    int ex = wbase + incl - p;
    excl[2 * t] = ex;
    excl[2 * t + 1] = ex + h0;
    __syncthreads();

    // scatter into LDS stage (bucket-relative positions)
#pragma unroll
    for (int c = 0; c < NSUB * SPT; ++c) {
        unsigned rk = rkv[c];
        if (rk != 0xFFFFFFFFu) {
            int key = (int)(rk & 0x7FFu);
            int r = (int)(rk >> 11);
            stage[excl[key] + r] = srcv[c];
        }
    }

    // per-node stats (cnt/excl are stable; independent of stage)
    if (t < 512) {
        int g = (b << 9) + t;
        if (g < NN) {
            int c0 = cnt[4 * t];
            int c1 = cnt[4 * t + 1];
            int c2 = cnt[4 * t + 2];
            int c3 = cnt[4 * t + 3];
            int extra = 0;
            for (int k = 0; k < nov; ++k) extra += ((int)(ovf[k] >> 32) == g);
            dinv[g] = rsqrtf((float)(c0 + c1 + c2 + c3 + extra) + 1.0f);
            rsg[g] = b * CCAP + excl[4 * t];                 // csr row start (absolute)
            spl[g] = (unsigned)c0 | ((unsigned)c1 << 8) |
                     ((unsigned)c2 << 16) | ((unsigned)c3 << 24);
        }
    }
    __syncthreads();

    // coalesced uint4 write-out (pad to 16B; garbage pad stays in-bucket)
    int total = excl[2047] + cnt[2047];
    int tot4 = (total + 3) >> 2;
    const uint4* st4 = (const uint4*)stage;
    uint4* csr4 = (uint4*)(csr + (size_t)b * CCAP);
#pragma unroll
    for (int k = 0; k < (CCAP / 4 + 1023) / 1024; ++k) {
        int i4 = k * 1024 + t;
        if (i4 < tot4) csr4[i4] = st4[i4];
    }
}

// xph[s] = fp16(dinv[s]*x[s]) padded to 16 halves (one aligned 32B row).
__global__ void k_prep(const float* __restrict__ x, const float* __restrict__ dinv,
                       __half* __restrict__ xph) {
    int i = blockIdx.x * blockDim.x + threadIdx.x;
    if (i >= NN * 16) return;
    int node = i >> 4;
    int c = i & 15;
    float v = (c < IC) ? dinv[node] * x[node * IC + c] : 0.0f;
    xph[i] = __float2half(v);
}

// Layer-1 aggregation, phases pbase..pbase+1. Phase chosen from XCC_ID
// (XCDs 0-3 -> first, 4-7 -> second) + per-phase atomic chunk cursors:
// 2-try grab covers all chunks for ANY preference split (proof in journal).
// Each XCD gathers from ONE 1.6MB phase region, drift-proof. partial buffer
// index = phase&1; acc=1 (second launch) read-modify-writes. 4 lanes/node.
__global__ __launch_bounds__(256) void k_agg1(const int* __restrict__ rsg,
                                              const unsigned* __restrict__ spl,
                                              const unsigned* __restrict__ csr,
                                              const __half* __restrict__ xph,
                                              float* __restrict__ partial,
                                              int* __restrict__ gcur,
                                              int pbase, int cbase, int acc) {
    __shared__ int sw[2];
    int t = threadIdx.x;
    if (t == 0) {
        int* cur = gcur + (NSEG + 1 + cbase) * GSTR;
        int pref = (xcc_id() >> 2) & 1;
        int idx = atomicAdd(&cur[pref * GSTR], 1);
        int p = pref;
        if (idx >= NAGG) {
            p = pref ^ 1;
            idx = atomicAdd(&cur[p * GSTR], 1);
        }
        sw[0] = idx;
        sw[1] = p;
    }
    __syncthreads();
    int blk = sw[0];
    if (blk >= NAGG) return;  // both phases fully claimed
    int q2 = sw[1];
    int ph = pbase + q2;

    int g = t >> 2;
    int qq = t & 3;
    int i = blk * 64 + g;
    unsigned sp = spl[i];
    int c0 = (int)(sp & 255u);
    int c1 = (int)((sp >> 8) & 255u);
    int c2 = (int)((sp >> 16) & 255u);
    int c3 = (int)(sp >> 24);
    int off = (ph > 0 ? c0 : 0) + (ph > 1 ? c1 : 0) + (ph > 2 ? c2 : 0);
    int len = ph == 0 ? c0 : ph == 1 ? c1 : ph == 2 ? c2 : c3;
    int beg = rsg[i] + off;
    int end = beg + len;

    float ax = 0.0f, ay = 0.0f, az = 0.0f, aw = 0.0f;
    int j = beg;
    for (; j + 1 < end; j += 2) {
        int s0 = csr[j];
        int s1 = csr[j + 1];
        uint2 u0 = *(const uint2*)(xph + (size_t)s0 * 16 + 4 * qq);
        uint2 u1 = *(const uint2*)(xph + (size_t)s1 * 16 + 4 * qq);
        float2 f0 = __half22float2(*(__half2*)&u0.x);
        float2 f1 = __half22float2(*(__half2*)&u0.y);
        float2 f2 = __half22float2(*(__half2*)&u1.x);
        float2 f3 = __half22float2(*(__half2*)&u1.y);
        ax += f0.x + f2.x;
        ay += f0.y + f2.y;
        az += f1.x + f3.x;
        aw += f1.y + f3.y;
    }
    if (j < end) {
        int s0 = csr[j];
        uint2 u0 = *(const uint2*)(xph + (size_t)s0 * 16 + 4 * qq);
        float2 f0 = __half22float2(*(__half2*)&u0.x);
        float2 f1 = __half22float2(*(__half2*)&u0.y);
        ax += f0.x;
        ay += f0.y;
        az += f1.x;
        aw += f1.y;
    }
    f4v r = {ax, ay, az, aw};
    float* dst = partial + ((size_t)(ph & 1) * NN + i) * 16 + 4 * qq;
    if (acc) {
        f4v o = __builtin_nontemporal_load((const f4v*)dst);  // zero-reuse stream
        r += o;
    }
    __builtin_nontemporal_store(r, (f4v*)dst);
}

// Sum phase partials + self loop + overflow-list fixup, then the fused MLP.
__global__ __launch_bounds__(256) void k_mlp(const float* __restrict__ partial,
                                             const __half* __restrict__ xph,
                                             const int* __restrict__ gcur,
                                             const ull* __restrict__ ovf,
                                             const float* __restrict__ dinv,
                                             const float* __restrict__ W1,
                                             const float* __restrict__ b1,
                                             const float* __restrict__ W2,
                                             const float* __restrict__ b2,
                                             float2* __restrict__ h2bp,
                                             float2* __restrict__ selfout) {
    __shared__ float sW1[IC * HC];
    __shared__ float sb1[HC];
    __shared__ float sW2[HC * OC];
    __shared__ float sb2[OC];
    int t = threadIdx.x;
    if (t < IC * HC) sW1[t] = W1[t];
    if (t < HC) sb1[t] = b1[t];
    if (t < HC * OC) sW2[t] = W2[t];
    if (t < OC) sb2[t] = b2[t];
    __syncthreads();

    int i = blockIdx.x * 256 + t;
    if (i >= NN) return;

    float dv = dinv[i];
    const float4* p0 = (const float4*)(partial + (size_t)i * 16);
    const float4* p1 = (const float4*)(partial + ((size_t)NN + i) * 16);
    const uint2* sp = (const uint2*)(xph + (size_t)i * 16);

    float agg[16];
#pragma unroll
    for (int c4 = 0; c4 < 4; ++c4) {
        float4 a = p0[c4];
        float4 b = p1[c4];
        uint2 u = sp[c4];
        float2 s0 = __half22float2(*(__half2*)&u.x);
        float2 s1 = __half22float2(*(__half2*)&u.y);
        agg[4 * c4 + 0] = a.x + b.x + s0.x;
        agg[4 * c4 + 1] = a.y + b.y + s0.y;
        agg[4 * c4 + 2] = a.z + b.z + s1.x;
        agg[4 * c4 + 3] = a.w + b.w + s1.y;
    }

    // overflow fixup (nov==0 in practice)
    int nov = min(gcur[NSEG * GSTR], OVFCAP);
    for (int k = 0; k < nov; ++k) {
        ull e = ovf[k];
        if ((int)(e >> 32) == i) {
            int s = (int)(e & 0xFFFFFFFFu);
            for (int c = 0; c < IC; ++c)
                agg[c] += __half2float(xph[(size_t)s * 16 + c]);
        }
    }

    float tt[IC];
#pragma unroll
    for (int c = 0; c < IC; ++c) tt[c] = dv * agg[c];

    float r[HC];
#pragma unroll
    for (int f = 0; f < HC; ++f) {
        float a = sb1[f];
#pragma unroll
        for (int c = 0; c < IC; ++c) a = fmaf(tt[c], sW1[c * HC + f], a);
        r[f] = fmaxf(a, 0.0f);
    }

    float o0 = 0.0f, o1 = 0.0f;
#pragma unroll
    for (int f = 0; f < HC; ++f) {
        o0 = fmaf(r[f], sW2[f * OC + 0], o0);
        o1 = fmaf(r[f], sW2[f * OC + 1], o1);
    }
    h2bp[i] = make_float2(o0 * dv, o1 * dv);  // dinv-prescaled for layer 2
    selfout[i] = make_float2(o0 * dv * dv + sb2[0], o1 * dv * dv + sb2[1]);
}

// layer-2: out[i] = selfout[i] + dinv[i] * (sum h2bp[src] + ovf matches).
// 4 lanes per node (stride-4 interleaved walk), 2-way unroll -> short
// dependent chains + plenty of loads in flight; shfl_xor(1,2) combine.
__global__ __launch_bounds__(256) void k_agg2(const int* __restrict__ rsg,
                                              const unsigned* __restrict__ spl,
                                              const unsigned* __restrict__ csr,
                                              const int* __restrict__ gcur,
                                              const ull* __restrict__ ovf,
                                              const float* __restrict__ dinv,
                                              const float2* __restrict__ h2bp,
                                              const float2* __restrict__ selfout,
                                              float2* __restrict__ out) {
    int tt = blockIdx.x * 256 + threadIdx.x;
    int i = tt >> 2;
    int h = tt & 3;
    if (i >= NN) return;
    unsigned sp = spl[i];
    int tot = (int)(sp & 255u) + (int)((sp >> 8) & 255u) +
              (int)((sp >> 16) & 255u) + (int)(sp >> 24);
    int beg = rsg[i];
    int end = beg + tot;
    float ax = 0.0f, ay = 0.0f;
    int j = beg + h;
    for (; j + 4 < end; j += 8) {
        int s0 = csr[j];
        int s1 = csr[j + 4];
        float2 h0 = h2bp[s0];
        float2 h1 = h2bp[s1];
        ax += h0.x + h1.x;
        ay += h0.y + h1.y;
    }
    if (j < end) {
        float2 h0 = h2bp[csr[j]];
        ax += h0.x;
        ay += h0.y;
    }
    ax += __shfl_xor(ax, 1);
    ay += __shfl_xor(ay, 1);
    ax += __shfl_xor(ax, 2);
    ay += __shfl_xor(ay, 2);
    if (h == 0) {
        // overflow fixup (nov==0 in practice); h2bp already dinv[src]-prescaled
        int nov = min(gcur[NSEG * GSTR], OVFCAP);
        for (int k = 0; k < nov; ++k) {
            ull e = ovf[k];
            if ((int)(e >> 32) == i) {
                float2 hh = h2bp[(int)(e & 0xFFFFFFFFu)];
                ax += hh.x;
                ay += hh.y;
            }
        }
        float dv = dinv[i];
        float2 so = selfout[i];
        out[i] = make_float2(so.x + dv * ax, so.y + dv * ay);
    }
}

extern "C" void kernel_launch(void* const* d_in, const int* in_sizes, int n_in,
                              void* d_out, int out_size, void* d_ws, size_t ws_size,
                              hipStream_t stream) {
    const float* x = (const float*)d_in[0];
    const void* ei = d_in[1];
    // d_in[2] = edge_attr (unused)
    const float* W1 = (const float*)d_in[3];
    const float* b1 = (const float*)d_in[4];
    const float* W2 = (const float*)d_in[5];
    const float* b2 = (const float*)d_in[6];
    float* out = (float*)d_out;

    ull* ovf = (ull*)d_ws;                              // OVFCAP       (0.5MB)
    int* gcur = (int*)(ovf + OVFCAP);                   // (NSEG+5)*16 ints
    int* flag = gcur + (NSEG + 5) * GSTR;               // 4
    int* rsg = flag + 4;                                // NN
    unsigned* spl = (unsigned*)(rsg + NN);              // NN
    float* dinv = (float*)(spl + NN);                   // NN
    __half* xph = (__half*)(dinv + NN);                 // NN*16 halves (6.4MB)
    float2* h2bp = (float2*)(xph + (size_t)NN * 16);    // NN
    float2* selfout = h2bp + NN;                        // NN
    unsigned* binned = (unsigned*)(selfout + NN);       // NSEG*SCAP    (35.3MB)
    float* partial = (float*)binned;                    // 2*NN*16 f32 (25.6MB), overlays
                                                        // binned (dead after k_sort)
    unsigned* csr = binned + (size_t)NSEG * SCAP;       // NBK*CCAP     (35.3MB)

    k_init<<<(NSEG + 5 + 255) / 256, 256, 0, stream>>>(gcur, ei, flag);
    k_binA<<<NTILE, BTH, 0, stream>>>(ei, flag, gcur, binned, ovf);
    k_sort<<<NBK, 1024, 0, stream>>>(gcur, binned, ovf, csr, dinv, rsg, spl);
    k_prep<<<(NN * 16 + 255) / 256, 256, 0, stream>>>(x, dinv, xph);
    k_agg1<<<2 * NAGG, 256, 0, stream>>>(rsg, spl, csr, xph, partial, gcur, 0, 0, 0);
    k_agg1<<<2 * NAGG, 256, 0, stream>>>(rsg, spl, csr, xph, partial, gcur, 2, 2, 1);
    k_mlp<<<NB, 256, 0, stream>>>(partial, xph, gcur, ovf, dinv, W1, b1, W2, b2,
                                  h2bp, selfout);
    k_agg2<<<(NN * 4 + 255) / 256, 256, 0, stream>>>(rsg, spl, csr, gcur, ovf, dinv,
                                                     h2bp, selfout, (float2*)out);
}

// Round 8
// 298.962 us; speedup vs baseline: 1.1846x; 1.1846x over previous
//
#include <hip/hip_runtime.h>
#include <hip/hip_fp16.h>

// GCN 2-layer: N=200000, E=6400000, 14 -> 16(relu) -> 2.
// Round 20: revert agg1 cursor scheme (FETCH identical under drift-proof
// mapping -> XCD-affinity hypothesis falsified; ticket atomics cost +20us per
// launch), and delete the partial round-trip instead:
//   - agg1 launch A = round-6 parity form (q2=bid&1, nt store, no atomics).
//   - launch B (k_agg1m) fuses phases 2+3 (contiguous in csr!) + partial
//     nt-read + self-loop + the whole MLP: agg exchanged via padded LDS tile,
//     4 hidden units per lane, shfl_xor(1,2) combine. Writes only
//     h2bp/selfout (3.2MB). k_mlp launch deleted (-51.2MB re-read, -25.6MB
//     partial write).
//   - binA keeps XCC_ID sub-segment (appends merge in local L2).
// Pipeline: init -> binA -> sort(+dinv) -> prep -> agg1A -> agg1m -> agg2.

constexpr int NN = 200000;
constexpr int NE = 6400000;
constexpr int IC = 14;
constexpr int HC = 16;
constexpr int OC = 2;

constexpr int NBK = 392;                   // buckets of 512 dst nodes
constexpr int NSUB = 8;                    // sub-segments per bucket (= XCD id)
constexpr int SCAP = 2816;                 // per (sub,bucket) cap: mean 2058 + 16.7 sigma
constexpr int NSEG = NSUB * NBK;           // 3136 segments
constexpr int CCAP = NSUB * SCAP;          // 22528 csr per-bucket capacity
constexpr int SPT = (SCAP + 1023) / 1024;  // 3 reg slots per (thread, segment)
constexpr int TILE = 5120;                 // edges per binA tile
constexpr int BTH = 512;                   // binA threads
constexpr int IPT = TILE / BTH;            // 10
constexpr int IPT2 = IPT / 2;              // 5 pair-loads per thread
constexpr int NTILE = NE / TILE;           // 1250
constexpr int OVFCAP = 65536;
constexpr int NAGG = NN / 64;              // 3125 chunks per phase
constexpr int GSTR = 16;                   // gcur stride: 1 counter per 64B line

typedef unsigned long long ull;
typedef float f4v __attribute__((ext_vector_type(4)));

__device__ __forceinline__ int phase_of(unsigned src) {
    return src >= 100000u ? (src >= 150000u ? 3 : 2) : (src >= 50000u ? 1 : 0);
}

// Physical XCD id (0..7). Affinity heuristic only -- correctness never
// depends on the value (G16): binA has the overflow path.
__device__ __forceinline__ int xcc_id() {
    int x;
    asm volatile("s_getreg_b32 %0, hwreg(HW_REG_XCC_ID)" : "=s"(x));
    return x & 7;
}

// init gcur (padded) + ovf counter + dtype flag
__global__ void k_init(int* __restrict__ gcur, const void* __restrict__ ei,
                       int* __restrict__ flag) {
    int i = blockIdx.x * blockDim.x + threadIdx.x;
    if (i < NSEG) gcur[i * GSTR] = i * SCAP;
    else if (i <= NSEG + 4) gcur[i * GSTR] = 0;  // ovf counter (+spare)
    if (i == 500) {  // one thread sniffs edge dtype
        const ull* p = (const ull*)ei;
        ull acc = 0ULL;
        for (int k = 0; k < 64; ++k) acc |= (p[k] >> 32);
        *flag = (acc == 0ULL) ? 1 : 0;  // 1 => int64 indices, 0 => int32
    }
}

// Bin edges by dst>>9 into per-(sub,bucket) global segments, sub = XCC_ID.
// Single pass over edges: dst+src pair-loaded, rank captured from the
// histogram atomic, both held in regs across the scan. LDS-staged for
// coalesced segment write-out.
__global__ __launch_bounds__(BTH, 8) void k_binA(const void* __restrict__ ei,
                                                 const int* __restrict__ flag,
                                                 int* __restrict__ gcur,
                                                 unsigned* __restrict__ binned,
                                                 ull* __restrict__ ovf) {
    __shared__ int hist[NBK];
    __shared__ int lofs[NBK];
    __shared__ int gofs[NBK];
    __shared__ int wsum[BTH / 64];
    __shared__ unsigned stage[TILE];

    int t = threadIdx.x;
    int fl = *flag;
    int tile0 = blockIdx.x * TILE;
    int segbase = xcc_id() * NBK;

    if (t < NBK) hist[t] = 0;
    __syncthreads();

    // single pass: dst+src pairs (16B loads), hist atomic rank capture.
    // pk = (dlow<<18)|src ; ra = (rank<<9)|bucket  (rank<5120 fits 13 bits)
    unsigned pk[IPT];
    unsigned ra[IPT];
#pragma unroll
    for (int k = 0; k < IPT2; ++k) {
        int e = tile0 + k * (2 * BTH) + 2 * t;
        int d0, d1, s0, s1;
        if (fl) {
            ulonglong2 dd = *(const ulonglong2*)((const long long*)ei + NE + e);
            ulonglong2 ss = *(const ulonglong2*)((const long long*)ei + e);
            d0 = (int)dd.x;
            d1 = (int)dd.y;
            s0 = (int)ss.x;
            s1 = (int)ss.y;
        } else {
            uint2 dd = *(const uint2*)((const int*)ei + NE + e);
            uint2 ss = *(const uint2*)((const int*)ei + e);
            d0 = (int)dd.x;
            d1 = (int)dd.y;
            s0 = (int)ss.x;
            s1 = (int)ss.y;
        }
        int b0 = d0 >> 9, b1 = d1 >> 9;
        int r0 = atomicAdd(&hist[b0], 1);
        int r1 = atomicAdd(&hist[b1], 1);
        pk[2 * k] = ((unsigned)(d0 & 511) << 18) | (unsigned)s0;
        pk[2 * k + 1] = ((unsigned)(d1 & 511) << 18) | (unsigned)s1;
        ra[2 * k] = ((unsigned)r0 << 9) | (unsigned)b0;
        ra[2 * k + 1] = ((unsigned)r1 << 9) | (unsigned)b1;
    }
    __syncthreads();

    // exclusive scan of 392 counts: pair-sum + 64-lane shfl scan + wave combine
    int h0 = 0, h1 = 0, p = 0;
    if (t < NBK / 2) {
        h0 = hist[2 * t];
        h1 = hist[2 * t + 1];
        p = h0 + h1;
    }
    int lane = t & 63;
    int w = t >> 6;
    int incl = p;
#pragma unroll
    for (int off = 1; off < 64; off <<= 1) {
        int v = __shfl_up(incl, off, 64);
        if (lane >= off) incl += v;
    }
    if (lane == 63) wsum[w] = incl;
    __syncthreads();
    int wbase = 0;
#pragma unroll
    for (int ww = 0; ww < BTH / 64; ++ww) wbase += (ww < w) ? wsum[ww] : 0;
    int ex = wbase + incl - p;
    if (t < NBK / 2) {
        lofs[2 * t] = ex;
        lofs[2 * t + 1] = ex + h0;
    }
    if (t < NBK) gofs[t] = atomicAdd(&gcur[(segbase + t) * GSTR], hist[t]);
    __syncthreads();

    // stage from regs at lofs[bucket] + rank (no global loads)
#pragma unroll
    for (int k = 0; k < IPT; ++k) {
        int b = (int)(ra[k] & 511u);
        int r = (int)(ra[k] >> 9);
        stage[lofs[b] + r] = pk[k];
    }
    __syncthreads();

    // coalesced write-out; bucket of slot i via seeded search on lofs
    for (int i = t; i < TILE; i += BTH) {
        int b = (i * 313) >> 12;  // ~ i / 13.06 (mean slots per bucket)
        if (b > NBK - 1) b = NBK - 1;
        while (b < NBK - 1 && lofs[b + 1] <= i) ++b;
        while (lofs[b] > i) --b;
        unsigned pack = stage[i];
        int seg = segbase + b;
        int dest = gofs[b] + (i - lofs[b]);
        if (dest < (seg + 1) * SCAP) {
            binned[dest] = pack;
        } else {  // overflow (never in practice)
            int op = atomicAdd(&gcur[NSEG * GSTR], 1);
            if (op < OVFCAP) {
                int d = (b << 9) | (int)(pack >> 18);
                int s = (int)(pack & 0x3FFFF);
                ovf[op] = ((ull)d << 32) | (unsigned)s;
            }
        }
    }
}

// bucket-local counting sort over 8 sub-segments, key = (dlow<<2)|phase(src).
// Single pass: rank captured from cnt atomic, (src, rank|key) in regs
// (static 8x3 slots); scatter into LDS stage at excl[key]+rank; coalesced
// uint4 write-out (every csr line written once -> no write amplification).
// Also computes dinv = rsqrt(degree+1) and packs 4x8-bit phase counts.
__global__ __launch_bounds__(1024, 4) void k_sort(const int* __restrict__ gcur,
                                                  const unsigned* __restrict__ binned,
                                                  const ull* __restrict__ ovf,
                                                  unsigned* __restrict__ csr,
                                                  float* __restrict__ dinv,
                                                  int* __restrict__ rsg,
                                                  unsigned* __restrict__ spl) {
    __shared__ int cnt[2048];
    __shared__ int excl[2048];
    __shared__ int wsum[16];
    __shared__ int nseg[NSUB];
    __shared__ unsigned stage[CCAP];      // 88KB sorted bucket staging
    int b = blockIdx.x;
    int t = threadIdx.x;
    cnt[t] = 0;
    cnt[t + 1024] = 0;
    if (t < NSUB) {
        int seg = t * NBK + b;
        nseg[t] = min(gcur[seg * GSTR] - seg * SCAP, SCAP);
    }
    __syncthreads();
    int nov = min(gcur[NSEG * GSTR], OVFCAP);

    // single pass: load + key + rank capture; held in regs (static indexing)
    unsigned srcv[NSUB * SPT];
    unsigned rkv[NSUB * SPT];
#pragma unroll
    for (int s = 0; s < NSUB; ++s) {
        int n = nseg[s];
        int sb = (s * NBK + b) * SCAP;
#pragma unroll
        for (int k = 0; k < SPT; ++k) {
            int i = k * 1024 + t;
            rkv[s * SPT + k] = 0xFFFFFFFFu;
            if (i < n) {
                unsigned pack = binned[sb + i];
                unsigned src = pack & 0x3FFFFu;
                int key = ((int)(pack >> 18) << 2) | phase_of(src);
                int r = atomicAdd(&cnt[key], 1);
                srcv[s * SPT + k] = src;
                rkv[s * SPT + k] = ((unsigned)r << 11) | (unsigned)key;
            }
        }
    }
    __syncthreads();

    // exclusive scan of 2048 counts: pair-sum + 1024-lane scan (16 waves)
    int h0 = cnt[2 * t];
    int h1 = cnt[2 * t + 1];
    int p = h0 + h1;
    int lane = t & 63;
    int w = t >> 6;
    int incl = p;
#pragma unroll
    for (int off = 1; off < 64; off <<= 1) {
        int v = __shfl_up(incl, off, 64);
        if (lane >= off) incl += v;
    }
    if (lane == 63) wsum[w] = incl;
    __syncthreads();
    int wbase = 0;
#pragma unroll
    for (int ww = 0; ww < 16; ++ww) wbase += (ww < w) ? wsum[ww] : 0;
    int ex = wbase + incl - p;
    excl[2 * t] = ex;
    excl[2 * t + 1] = ex + h0;
    __syncthreads();

    // scatter into LDS stage (bucket-relative positions)
#pragma unroll
    for (int c = 0; c < NSUB * SPT; ++c) {
        unsigned rk = rkv[c];
        if (rk != 0xFFFFFFFFu) {
            int key = (int)(rk & 0x7FFu);
            int r = (int)(rk >> 11);
            stage[excl[key] + r] = srcv[c];
        }
    }

    // per-node stats (cnt/excl are stable; independent of stage)
    if (t < 512) {
        int g = (b << 9) + t;
        if (g < NN) {
            int c0 = cnt[4 * t];
            int c1 = cnt[4 * t + 1];
            int c2 = cnt[4 * t + 2];
            int c3 = cnt[4 * t + 3];
            int extra = 0;
            for (int k = 0; k < nov; ++k) extra += ((int)(ovf[k] >> 32) == g);
            dinv[g] = rsqrtf((float)(c0 + c1 + c2 + c3 + extra) + 1.0f);
            rsg[g] = b * CCAP + excl[4 * t];                 // csr row start (absolute)
            spl[g] = (unsigned)c0 | ((unsigned)c1 << 8) |
                     ((unsigned)c2 << 16) | ((unsigned)c3 << 24);
        }
    }
    __syncthreads();

    // coalesced uint4 write-out (pad to 16B; garbage pad stays in-bucket)
    int total = excl[2047] + cnt[2047];
    int tot4 = (total + 3) >> 2;
    const uint4* st4 = (const uint4*)stage;
    uint4* csr4 = (uint4*)(csr + (size_t)b * CCAP);
#pragma unroll
    for (int k = 0; k < (CCAP / 4 + 1023) / 1024; ++k) {
        int i4 = k * 1024 + t;
        if (i4 < tot4) csr4[i4] = st4[i4];
    }
}

// xph[s] = fp16(dinv[s]*x[s]) padded to 16 halves (one aligned 32B row).
__global__ void k_prep(const float* __restrict__ x, const float* __restrict__ dinv,
                       __half* __restrict__ xph) {
    int i = blockIdx.x * blockDim.x + threadIdx.x;
    if (i >= NN * 16) return;
    int node = i >> 4;
    int c = i & 15;
    float v = (c < IC) ? dinv[node] * x[node * IC + c] : 0.0f;
    xph[i] = __float2half(v);
}

// Layer-1 aggregation launch A: phases {0,1}, q2 = bid&1 (parity heuristic,
// round-6 measured form). nt stores into partial[q2]. 4 lanes per dst node.
__global__ __launch_bounds__(256) void k_agg1(const int* __restrict__ rsg,
                                              const unsigned* __restrict__ spl,
                                              const unsigned* __restrict__ csr,
                                              const __half* __restrict__ xph,
                                              float* __restrict__ partial) {
    int t = threadIdx.x;
    int q2 = blockIdx.x & 1;
    int blk = blockIdx.x >> 1;
    int g = t >> 2;
    int qq = t & 3;
    int i = blk * 64 + g;
    unsigned sp = spl[i];
    int c0 = (int)(sp & 255u);
    int c1 = (int)((sp >> 8) & 255u);
    int beg = rsg[i] + (q2 ? c0 : 0);
    int end = beg + (q2 ? c1 : c0);

    float ax = 0.0f, ay = 0.0f, az = 0.0f, aw = 0.0f;
    int j = beg;
    for (; j + 1 < end; j += 2) {
        int s0 = csr[j];
        int s1 = csr[j + 1];
        uint2 u0 = *(const uint2*)(xph + (size_t)s0 * 16 + 4 * qq);
        uint2 u1 = *(const uint2*)(xph + (size_t)s1 * 16 + 4 * qq);
        float2 f0 = __half22float2(*(__half2*)&u0.x);
        float2 f1 = __half22float2(*(__half2*)&u0.y);
        float2 f2 = __half22float2(*(__half2*)&u1.x);
        float2 f3 = __half22float2(*(__half2*)&u1.y);
        ax += f0.x + f2.x;
        ay += f0.y + f2.y;
        az += f1.x + f3.x;
        aw += f1.y + f3.y;
    }
    if (j < end) {
        int s0 = csr[j];
        uint2 u0 = *(const uint2*)(xph + (size_t)s0 * 16 + 4 * qq);
        float2 f0 = __half22float2(*(__half2*)&u0.x);
        float2 f1 = __half22float2(*(__half2*)&u0.y);
        ax += f0.x;
        ay += f0.y;
        az += f1.x;
        aw += f1.y;
    }
    f4v r = {ax, ay, az, aw};
    __builtin_nontemporal_store(r, (f4v*)(partial + ((size_t)q2 * NN + i) * 16 + 4 * qq));
}

// Launch B: phases {2,3} (contiguous csr range) + partial nt-read + self-loop
// + overflow fixup + fused MLP. agg exchanged via +1-padded LDS tile; each
// lane computes 4 hidden units; shfl_xor(1,2) combines the output dot.
// Writes only h2bp/selfout (3.2MB). Replaces k_mlp entirely.
__global__ __launch_bounds__(256) void k_agg1m(const int* __restrict__ rsg,
                                               const unsigned* __restrict__ spl,
                                               const unsigned* __restrict__ csr,
                                               const __half* __restrict__ xph,
                                               const float* __restrict__ partial,
                                               const int* __restrict__ gcur,
                                               const ull* __restrict__ ovf,
                                               const float* __restrict__ dinv,
                                               const float* __restrict__ W1,
                                               const float* __restrict__ b1,
                                               const float* __restrict__ W2,
                                               const float* __restrict__ b2,
                                               float2* __restrict__ h2bp,
                                               float2* __restrict__ selfout) {
    __shared__ float sW1[IC * HC];
    __shared__ float sb1[HC];
    __shared__ float sW2[HC * OC];
    __shared__ float sb2[OC];
    __shared__ float sAgg[64][17];  // +1 pad: spread rows across banks
    int t = threadIdx.x;
    if (t < IC * HC) sW1[t] = W1[t];
    if (t < HC) sb1[t] = b1[t];
    if (t < HC * OC) sW2[t] = W2[t];
    if (t < OC) sb2[t] = b2[t];

    int g = t >> 2;
    int qq = t & 3;
    int i = blockIdx.x * 64 + g;   // NN = 3125*64 exactly
    unsigned sp = spl[i];
    int c0 = (int)(sp & 255u);
    int c1 = (int)((sp >> 8) & 255u);
    int c2 = (int)((sp >> 16) & 255u);
    int c3 = (int)(sp >> 24);
    int beg = rsg[i] + c0 + c1;    // phases 2+3 are contiguous
    int end = beg + c2 + c3;

    float ax = 0.0f, ay = 0.0f, az = 0.0f, aw = 0.0f;
    int j = beg;
    for (; j + 1 < end; j += 2) {
        int s0 = csr[j];
        int s1 = csr[j + 1];
        uint2 u0 = *(const uint2*)(xph + (size_t)s0 * 16 + 4 * qq);
        uint2 u1 = *(const uint2*)(xph + (size_t)s1 * 16 + 4 * qq);
        float2 f0 = __half22float2(*(__half2*)&u0.x);
        float2 f1 = __half22float2(*(__half2*)&u0.y);
        float2 f2 = __half22float2(*(__half2*)&u1.x);
        float2 f3 = __half22float2(*(__half2*)&u1.y);
        ax += f0.x + f2.x;
        ay += f0.y + f2.y;
        az += f1.x + f3.x;
        aw += f1.y + f3.y;
    }
    if (j < end) {
        int s0 = csr[j];
        uint2 u0 = *(const uint2*)(xph + (size_t)s0 * 16 + 4 * qq);
        float2 f0 = __half22float2(*(__half2*)&u0.x);
        float2 f1 = __half22float2(*(__half2*)&u0.y);
        ax += f0.x;
        ay += f0.y;
        az += f1.x;
        aw += f1.y;
    }

    // + phase-0/1 partials (one-shot streams) + self row
    f4v a0 = __builtin_nontemporal_load((const f4v*)(partial + (size_t)i * 16 + 4 * qq));
    f4v a1 = __builtin_nontemporal_load(
        (const f4v*)(partial + ((size_t)NN + i) * 16 + 4 * qq));
    uint2 us = *(const uint2*)(xph + (size_t)i * 16 + 4 * qq);
    float2 sx = __half22float2(*(__half2*)&us.x);
    float2 sy = __half22float2(*(__half2*)&us.y);
    float v0 = ax + a0.x + a1.x + sx.x;
    float v1 = ay + a0.y + a1.y + sx.y;
    float v2 = az + a0.z + a1.z + sy.x;
    float v3 = aw + a0.w + a1.w + sy.y;

    // overflow fixup (nov==0 in practice)
    int nov = min(gcur[NSEG * GSTR], OVFCAP);
    for (int k = 0; k < nov; ++k) {
        ull e = ovf[k];
        if ((int)(e >> 32) == i) {
            int s = (int)(e & 0xFFFFFFFFu);
            int ch = 4 * qq;
            v0 += __half2float(xph[(size_t)s * 16 + ch]);
            v1 += __half2float(xph[(size_t)s * 16 + ch + 1]);
            v2 += __half2float(xph[(size_t)s * 16 + ch + 2]);
            v3 += __half2float(xph[(size_t)s * 16 + ch + 3]);
        }
    }

    float dv = dinv[i];
    sAgg[g][4 * qq + 0] = dv * v0;
    sAgg[g][4 * qq + 1] = dv * v1;
    sAgg[g][4 * qq + 2] = dv * v2;
    sAgg[g][4 * qq + 3] = dv * v3;
    __syncthreads();

    // MLP: lane computes hidden units f = 4*qq .. 4*qq+3 (all lanes of a
    // node read the same sAgg row -> LDS broadcast).
    float o0 = 0.0f, o1 = 0.0f;
#pragma unroll
    for (int f4 = 0; f4 < 4; ++f4) {
        int f = 4 * qq + f4;
        float a = sb1[f];
#pragma unroll
        for (int c = 0; c < IC; ++c) a = fmaf(sAgg[g][c], sW1[c * HC + f], a);
        a = fmaxf(a, 0.0f);
        o0 = fmaf(a, sW2[f * OC + 0], o0);
        o1 = fmaf(a, sW2[f * OC + 1], o1);
    }
    o0 += __shfl_xor(o0, 1);
    o1 += __shfl_xor(o1, 1);
    o0 += __shfl_xor(o0, 2);
    o1 += __shfl_xor(o1, 2);
    if (qq == 0) {
        h2bp[i] = make_float2(o0 * dv, o1 * dv);  // dinv-prescaled for layer 2
        selfout[i] = make_float2(o0 * dv * dv + sb2[0], o1 * dv * dv + sb2[1]);
    }
}

// layer-2: out[i] = selfout[i] + dinv[i] * (sum h2bp[src] + ovf matches).
// 4 lanes per node (stride-4 interleaved walk), 2-way unroll -> short
// dependent chains + plenty of loads in flight; shfl_xor(1,2) combine.
__global__ __launch_bounds__(256) void k_agg2(const int* __restrict__ rsg,
                                              const unsigned* __restrict__ spl,
                                              const unsigned* __restrict__ csr,
                                              const int* __restrict__ gcur,
                                              const ull* __restrict__ ovf,
                                              const float* __restrict__ dinv,
                                              const float2* __restrict__ h2bp,
                                              const float2* __restrict__ selfout,
                                              float2* __restrict__ out) {
    int tt = blockIdx.x * 256 + threadIdx.x;
    int i = tt >> 2;
    int h = tt & 3;
    if (i >= NN) return;
    unsigned sp = spl[i];
    int tot = (int)(sp & 255u) + (int)((sp >> 8) & 255u) +
              (int)((sp >> 16) & 255u) + (int)(sp >> 24);
    int beg = rsg[i];
    int end = beg + tot;
    float ax = 0.0f, ay = 0.0f;
    int j = beg + h;
    for (; j + 4 < end; j += 8) {
        int s0 = csr[j];
        int s1 = csr[j + 4];
        float2 h0 = h2bp[s0];
        float2 h1 = h2bp[s1];
        ax += h0.x + h1.x;
        ay += h0.y + h1.y;
    }
    if (j < end) {
        float2 h0 = h2bp[csr[j]];
        ax += h0.x;
        ay += h0.y;
    }
    ax += __shfl_xor(ax, 1);
    ay += __shfl_xor(ay, 1);
    ax += __shfl_xor(ax, 2);
    ay += __shfl_xor(ay, 2);
    if (h == 0) {
        // overflow fixup (nov==0 in practice); h2bp already dinv[src]-prescaled
        int nov = min(gcur[NSEG * GSTR], OVFCAP);
        for (int k = 0; k < nov; ++k) {
            ull e = ovf[k];
            if ((int)(e >> 32) == i) {
                float2 hh = h2bp[(int)(e & 0xFFFFFFFFu)];
                ax += hh.x;
                ay += hh.y;
            }
        }
        float dv = dinv[i];
        float2 so = selfout[i];
        out[i] = make_float2(so.x + dv * ax, so.y + dv * ay);
    }
}

extern "C" void kernel_launch(void* const* d_in, const int* in_sizes, int n_in,
                              void* d_out, int out_size, void* d_ws, size_t ws_size,
                              hipStream_t stream) {
    const float* x = (const float*)d_in[0];
    const void* ei = d_in[1];
    // d_in[2] = edge_attr (unused)
    const float* W1 = (const float*)d_in[3];
    const float* b1 = (const float*)d_in[4];
    const float* W2 = (const float*)d_in[5];
    const float* b2 = (const float*)d_in[6];
    float* out = (float*)d_out;

    ull* ovf = (ull*)d_ws;                              // OVFCAP       (0.5MB)
    int* gcur = (int*)(ovf + OVFCAP);                   // (NSEG+5)*16 ints
    int* flag = gcur + (NSEG + 5) * GSTR;               // 4
    int* rsg = flag + 4;                                // NN
    unsigned* spl = (unsigned*)(rsg + NN);              // NN
    float* dinv = (float*)(spl + NN);                   // NN
    __half* xph = (__half*)(dinv + NN);                 // NN*16 halves (6.4MB)
    float2* h2bp = (float2*)(xph + (size_t)NN * 16);    // NN
    float2* selfout = h2bp + NN;                        // NN
    unsigned* binned = (unsigned*)(selfout + NN);       // NSEG*SCAP    (35.3MB)
    float* partial = (float*)binned;                    // 2*NN*16 f32 (25.6MB), overlays
                                                        // binned (dead after k_sort)
    unsigned* csr = binned + (size_t)NSEG * SCAP;       // NBK*CCAP     (35.3MB)

    k_init<<<(NSEG + 5 + 255) / 256, 256, 0, stream>>>(gcur, ei, flag);
    k_binA<<<NTILE, BTH, 0, stream>>>(ei, flag, gcur, binned, ovf);
    k_sort<<<NBK, 1024, 0, stream>>>(gcur, binned, ovf, csr, dinv, rsg, spl);
    k_prep<<<(NN * 16 + 255) / 256, 256, 0, stream>>>(x, dinv, xph);
    k_agg1<<<2 * NAGG, 256, 0, stream>>>(rsg, spl, csr, xph, partial);
    k_agg1m<<<NAGG, 256, 0, stream>>>(rsg, spl, csr, xph, partial, gcur, ovf, dinv,
                                      W1, b1, W2, b2, h2bp, selfout);
    k_agg2<<<(NN * 4 + 255) / 256, 256, 0, stream>>>(rsg, spl, csr, gcur, ovf, dinv,
                                                     h2bp, selfout, (float2*)out);
}

// Round 9
// 290.231 us; speedup vs baseline: 1.2203x; 1.0301x over previous
//
#include <hip/hip_runtime.h>
#include <hip/hip_fp16.h>

// GCN 2-layer: N=200000, E=6400000, 14 -> 16(relu) -> 2.
// Round 21: 8 lanes per node in all three gather kernels. Profile was flat
// (agg1m 50, binA 49.5, agg1A ~47, all <=21% HBM, <=18% VALU): latency-bound,
// chains of ~8 dependent csr->xph gather steps. Extra lane bit (eh) splits
// each node's edge range in half: chain halves, loads-in-flight double,
// grids double. Combine via one extra shfl_xor(4).
//   - agg1A: 32 nodes/block, lane = (qq channel slice, eh edge half).
//   - agg1m: same + MLP now 2 hidden units/lane, shfl_xor(1,2,4) combine.
//   - agg2: 8-way edge split, shfl_xor(1,2,4).
// Pipeline: init -> binA -> sort(+dinv) -> prep -> agg1A -> agg1m -> agg2.

constexpr int NN = 200000;
constexpr int NE = 6400000;
constexpr int IC = 14;
constexpr int HC = 16;
constexpr int OC = 2;

constexpr int NBK = 392;                   // buckets of 512 dst nodes
constexpr int NSUB = 8;                    // sub-segments per bucket (= XCD id)
constexpr int SCAP = 2816;                 // per (sub,bucket) cap: mean 2058 + 16.7 sigma
constexpr int NSEG = NSUB * NBK;           // 3136 segments
constexpr int CCAP = NSUB * SCAP;          // 22528 csr per-bucket capacity
constexpr int SPT = (SCAP + 1023) / 1024;  // 3 reg slots per (thread, segment)
constexpr int TILE = 5120;                 // edges per binA tile
constexpr int BTH = 512;                   // binA threads
constexpr int IPT = TILE / BTH;            // 10
constexpr int IPT2 = IPT / 2;              // 5 pair-loads per thread
constexpr int NTILE = NE / TILE;           // 1250
constexpr int OVFCAP = 65536;
constexpr int NM = NN / 32;                // 6250 blocks (32 nodes per block)
constexpr int GSTR = 16;                   // gcur stride: 1 counter per 64B line

typedef unsigned long long ull;
typedef float f4v __attribute__((ext_vector_type(4)));

__device__ __forceinline__ int phase_of(unsigned src) {
    return src >= 100000u ? (src >= 150000u ? 3 : 2) : (src >= 50000u ? 1 : 0);
}

// Physical XCD id (0..7). Affinity heuristic only -- correctness never
// depends on the value (G16): binA has the overflow path.
__device__ __forceinline__ int xcc_id() {
    int x;
    asm volatile("s_getreg_b32 %0, hwreg(HW_REG_XCC_ID)" : "=s"(x));
    return x & 7;
}

// init gcur (padded) + ovf counter + dtype flag
__global__ void k_init(int* __restrict__ gcur, const void* __restrict__ ei,
                       int* __restrict__ flag) {
    int i = blockIdx.x * blockDim.x + threadIdx.x;
    if (i < NSEG) gcur[i * GSTR] = i * SCAP;
    else if (i <= NSEG + 4) gcur[i * GSTR] = 0;  // ovf counter (+spare)
    if (i == 500) {  // one thread sniffs edge dtype
        const ull* p = (const ull*)ei;
        ull acc = 0ULL;
        for (int k = 0; k < 64; ++k) acc |= (p[k] >> 32);
        *flag = (acc == 0ULL) ? 1 : 0;  // 1 => int64 indices, 0 => int32
    }
}

// Bin edges by dst>>9 into per-(sub,bucket) global segments, sub = XCC_ID.
// Single pass over edges: dst+src pair-loaded, rank captured from the
// histogram atomic, both held in regs across the scan. LDS-staged for
// coalesced segment write-out.
__global__ __launch_bounds__(BTH, 8) void k_binA(const void* __restrict__ ei,
                                                 const int* __restrict__ flag,
                                                 int* __restrict__ gcur,
                                                 unsigned* __restrict__ binned,
                                                 ull* __restrict__ ovf) {
    __shared__ int hist[NBK];
    __shared__ int lofs[NBK];
    __shared__ int gofs[NBK];
    __shared__ int wsum[BTH / 64];
    __shared__ unsigned stage[TILE];

    int t = threadIdx.x;
    int fl = *flag;
    int tile0 = blockIdx.x * TILE;
    int segbase = xcc_id() * NBK;

    if (t < NBK) hist[t] = 0;
    __syncthreads();

    // single pass: dst+src pairs (16B loads), hist atomic rank capture.
    // pk = (dlow<<18)|src ; ra = (rank<<9)|bucket  (rank<5120 fits 13 bits)
    unsigned pk[IPT];
    unsigned ra[IPT];
#pragma unroll
    for (int k = 0; k < IPT2; ++k) {
        int e = tile0 + k * (2 * BTH) + 2 * t;
        int d0, d1, s0, s1;
        if (fl) {
            ulonglong2 dd = *(const ulonglong2*)((const long long*)ei + NE + e);
            ulonglong2 ss = *(const ulonglong2*)((const long long*)ei + e);
            d0 = (int)dd.x;
            d1 = (int)dd.y;
            s0 = (int)ss.x;
            s1 = (int)ss.y;
        } else {
            uint2 dd = *(const uint2*)((const int*)ei + NE + e);
            uint2 ss = *(const uint2*)((const int*)ei + e);
            d0 = (int)dd.x;
            d1 = (int)dd.y;
            s0 = (int)ss.x;
            s1 = (int)ss.y;
        }
        int b0 = d0 >> 9, b1 = d1 >> 9;
        int r0 = atomicAdd(&hist[b0], 1);
        int r1 = atomicAdd(&hist[b1], 1);
        pk[2 * k] = ((unsigned)(d0 & 511) << 18) | (unsigned)s0;
        pk[2 * k + 1] = ((unsigned)(d1 & 511) << 18) | (unsigned)s1;
        ra[2 * k] = ((unsigned)r0 << 9) | (unsigned)b0;
        ra[2 * k + 1] = ((unsigned)r1 << 9) | (unsigned)b1;
    }
    __syncthreads();

    // exclusive scan of 392 counts: pair-sum + 64-lane shfl scan + wave combine
    int h0 = 0, h1 = 0, p = 0;
    if (t < NBK / 2) {
        h0 = hist[2 * t];
        h1 = hist[2 * t + 1];
        p = h0 + h1;
    }
    int lane = t & 63;
    int w = t >> 6;
    int incl = p;
#pragma unroll
    for (int off = 1; off < 64; off <<= 1) {
        int v = __shfl_up(incl, off, 64);
        if (lane >= off) incl += v;
    }
    if (lane == 63) wsum[w] = incl;
    __syncthreads();
    int wbase = 0;
#pragma unroll
    for (int ww = 0; ww < BTH / 64; ++ww) wbase += (ww < w) ? wsum[ww] : 0;
    int ex = wbase + incl - p;
    if (t < NBK / 2) {
        lofs[2 * t] = ex;
        lofs[2 * t + 1] = ex + h0;
    }
    if (t < NBK) gofs[t] = atomicAdd(&gcur[(segbase + t) * GSTR], hist[t]);
    __syncthreads();

    // stage from regs at lofs[bucket] + rank (no global loads)
#pragma unroll
    for (int k = 0; k < IPT; ++k) {
        int b = (int)(ra[k] & 511u);
        int r = (int)(ra[k] >> 9);
        stage[lofs[b] + r] = pk[k];
    }
    __syncthreads();

    // coalesced write-out; bucket of slot i via seeded search on lofs
    for (int i = t; i < TILE; i += BTH) {
        int b = (i * 313) >> 12;  // ~ i / 13.06 (mean slots per bucket)
        if (b > NBK - 1) b = NBK - 1;
        while (b < NBK - 1 && lofs[b + 1] <= i) ++b;
        while (lofs[b] > i) --b;
        unsigned pack = stage[i];
        int seg = segbase + b;
        int dest = gofs[b] + (i - lofs[b]);
        if (dest < (seg + 1) * SCAP) {
            binned[dest] = pack;
        } else {  // overflow (never in practice)
            int op = atomicAdd(&gcur[NSEG * GSTR], 1);
            if (op < OVFCAP) {
                int d = (b << 9) | (int)(pack >> 18);
                int s = (int)(pack & 0x3FFFF);
                ovf[op] = ((ull)d << 32) | (unsigned)s;
            }
        }
    }
}

// bucket-local counting sort over 8 sub-segments, key = (dlow<<2)|phase(src).
// Single pass: rank captured from cnt atomic, (src, rank|key) in regs
// (static 8x3 slots); scatter into LDS stage at excl[key]+rank; coalesced
// uint4 write-out (every csr line written once -> no write amplification).
// Also computes dinv = rsqrt(degree+1) and packs 4x8-bit phase counts.
__global__ __launch_bounds__(1024, 4) void k_sort(const int* __restrict__ gcur,
                                                  const unsigned* __restrict__ binned,
                                                  const ull* __restrict__ ovf,
                                                  unsigned* __restrict__ csr,
                                                  float* __restrict__ dinv,
                                                  int* __restrict__ rsg,
                                                  unsigned* __restrict__ spl) {
    __shared__ int cnt[2048];
    __shared__ int excl[2048];
    __shared__ int wsum[16];
    __shared__ int nseg[NSUB];
    __shared__ unsigned stage[CCAP];      // 88KB sorted bucket staging
    int b = blockIdx.x;
    int t = threadIdx.x;
    cnt[t] = 0;
    cnt[t + 1024] = 0;
    if (t < NSUB) {
        int seg = t * NBK + b;
        nseg[t] = min(gcur[seg * GSTR] - seg * SCAP, SCAP);
    }
    __syncthreads();
    int nov = min(gcur[NSEG * GSTR], OVFCAP);

    // single pass: load + key + rank capture; held in regs (static indexing)
    unsigned srcv[NSUB * SPT];
    unsigned rkv[NSUB * SPT];
#pragma unroll
    for (int s = 0; s < NSUB; ++s) {
        int n = nseg[s];
        int sb = (s * NBK + b) * SCAP;
#pragma unroll
        for (int k = 0; k < SPT; ++k) {
            int i = k * 1024 + t;
            rkv[s * SPT + k] = 0xFFFFFFFFu;
            if (i < n) {
                unsigned pack = binned[sb + i];
                unsigned src = pack & 0x3FFFFu;
                int key = ((int)(pack >> 18) << 2) | phase_of(src);
                int r = atomicAdd(&cnt[key], 1);
                srcv[s * SPT + k] = src;
                rkv[s * SPT + k] = ((unsigned)r << 11) | (unsigned)key;
            }
        }
    }
    __syncthreads();

    // exclusive scan of 2048 counts: pair-sum + 1024-lane scan (16 waves)
    int h0 = cnt[2 * t];
    int h1 = cnt[2 * t + 1];
    int p = h0 + h1;
    int lane = t & 63;
    int w = t >> 6;
    int incl = p;
#pragma unroll
    for (int off = 1; off < 64; off <<= 1) {
        int v = __shfl_up(incl, off, 64);
        if (lane >= off) incl += v;
    }
    if (lane == 63) wsum[w] = incl;
    __syncthreads();
    int wbase = 0;
#pragma unroll
    for (int ww = 0; ww < 16; ++ww) wbase += (ww < w) ? wsum[ww] : 0;
    int ex = wbase + incl - p;
    excl[2 * t] = ex;
    excl[2 * t + 1] = ex + h0;
    __syncthreads();

    // scatter into LDS stage (bucket-relative positions)
#pragma unroll
    for (int c = 0; c < NSUB * SPT; ++c) {
        unsigned rk = rkv[c];
        if (rk != 0xFFFFFFFFu) {
            int key = (int)(rk & 0x7FFu);
            int r = (int)(rk >> 11);
            stage[excl[key] + r] = srcv[c];
        }
    }

    // per-node stats (cnt/excl are stable; independent of stage)
    if (t < 512) {
        int g = (b << 9) + t;
        if (g < NN) {
            int c0 = cnt[4 * t];
            int c1 = cnt[4 * t + 1];
            int c2 = cnt[4 * t + 2];
            int c3 = cnt[4 * t + 3];
            int extra = 0;
            for (int k = 0; k < nov; ++k) extra += ((int)(ovf[k] >> 32) == g);
            dinv[g] = rsqrtf((float)(c0 + c1 + c2 + c3 + extra) + 1.0f);
            rsg[g] = b * CCAP + excl[4 * t];                 // csr row start (absolute)
            spl[g] = (unsigned)c0 | ((unsigned)c1 << 8) |
                     ((unsigned)c2 << 16) | ((unsigned)c3 << 24);
        }
    }
    __syncthreads();

    // coalesced uint4 write-out (pad to 16B; garbage pad stays in-bucket)
    int total = excl[2047] + cnt[2047];
    int tot4 = (total + 3) >> 2;
    const uint4* st4 = (const uint4*)stage;
    uint4* csr4 = (uint4*)(csr + (size_t)b * CCAP);
#pragma unroll
    for (int k = 0; k < (CCAP / 4 + 1023) / 1024; ++k) {
        int i4 = k * 1024 + t;
        if (i4 < tot4) csr4[i4] = st4[i4];
    }
}

// xph[s] = fp16(dinv[s]*x[s]) padded to 16 halves (one aligned 32B row).
__global__ void k_prep(const float* __restrict__ x, const float* __restrict__ dinv,
                       __half* __restrict__ xph) {
    int i = blockIdx.x * blockDim.x + threadIdx.x;
    if (i >= NN * 16) return;
    int node = i >> 4;
    int c = i & 15;
    float v = (c < IC) ? dinv[node] * x[node * IC + c] : 0.0f;
    xph[i] = __float2half(v);
}

// Layer-1 aggregation launch A: phases {0,1}, q2 = bid&1. 8 lanes per node:
// qq = channel slice (t&3), eh = edge half ((t>>2)&1). shfl_xor(4) combines
// the halves; eh==0 lanes nt-store partial[q2]. 32 nodes per block.
__global__ __launch_bounds__(256) void k_agg1(const int* __restrict__ rsg,
                                              const unsigned* __restrict__ spl,
                                              const unsigned* __restrict__ csr,
                                              const __half* __restrict__ xph,
                                              float* __restrict__ partial) {
    int t = threadIdx.x;
    int q2 = blockIdx.x & 1;
    int blk = blockIdx.x >> 1;
    int g = t >> 3;
    int qq = t & 3;
    int eh = (t >> 2) & 1;
    int i = blk * 32 + g;
    unsigned sp = spl[i];
    int c0 = (int)(sp & 255u);
    int c1 = (int)((sp >> 8) & 255u);
    int beg = rsg[i] + (q2 ? c0 : 0);
    int end = beg + (q2 ? c1 : c0);

    float ax = 0.0f, ay = 0.0f, az = 0.0f, aw = 0.0f;
    int j = beg + eh;
    for (; j + 2 < end; j += 4) {
        int s0 = csr[j];
        int s1 = csr[j + 2];
        uint2 u0 = *(const uint2*)(xph + (size_t)s0 * 16 + 4 * qq);
        uint2 u1 = *(const uint2*)(xph + (size_t)s1 * 16 + 4 * qq);
        float2 f0 = __half22float2(*(__half2*)&u0.x);
        float2 f1 = __half22float2(*(__half2*)&u0.y);
        float2 f2 = __half22float2(*(__half2*)&u1.x);
        float2 f3 = __half22float2(*(__half2*)&u1.y);
        ax += f0.x + f2.x;
        ay += f0.y + f2.y;
        az += f1.x + f3.x;
        aw += f1.y + f3.y;
    }
    if (j < end) {
        int s0 = csr[j];
        uint2 u0 = *(const uint2*)(xph + (size_t)s0 * 16 + 4 * qq);
        float2 f0 = __half22float2(*(__half2*)&u0.x);
        float2 f1 = __half22float2(*(__half2*)&u0.y);
        ax += f0.x;
        ay += f0.y;
        az += f1.x;
        aw += f1.y;
    }
    ax += __shfl_xor(ax, 4);
    ay += __shfl_xor(ay, 4);
    az += __shfl_xor(az, 4);
    aw += __shfl_xor(aw, 4);
    if (eh == 0) {
        f4v r = {ax, ay, az, aw};
        __builtin_nontemporal_store(
            r, (f4v*)(partial + ((size_t)q2 * NN + i) * 16 + 4 * qq));
    }
}

// Launch B: phases {2,3} (contiguous csr range) + partial nt-read + self-loop
// + overflow fixup + fused MLP. 8 lanes per node (qq slice x eh half);
// shfl_xor(4) combines halves; padded LDS tile exchanges agg; 2 hidden units
// per lane, shfl_xor(1,2,4) combines the output dot. Writes h2bp/selfout.
__global__ __launch_bounds__(256) void k_agg1m(const int* __restrict__ rsg,
                                               const unsigned* __restrict__ spl,
                                               const unsigned* __restrict__ csr,
                                               const __half* __restrict__ xph,
                                               const float* __restrict__ partial,
                                               const int* __restrict__ gcur,
                                               const ull* __restrict__ ovf,
                                               const float* __restrict__ dinv,
                                               const float* __restrict__ W1,
                                               const float* __restrict__ b1,
                                               const float* __restrict__ W2,
                                               const float* __restrict__ b2,
                                               float2* __restrict__ h2bp,
                                               float2* __restrict__ selfout) {
    __shared__ float sW1[IC * HC];
    __shared__ float sb1[HC];
    __shared__ float sW2[HC * OC];
    __shared__ float sb2[OC];
    __shared__ float sAgg[32][17];  // +1 pad: spread rows across banks
    int t = threadIdx.x;
    if (t < IC * HC) sW1[t] = W1[t];
    if (t < HC) sb1[t] = b1[t];
    if (t < HC * OC) sW2[t] = W2[t];
    if (t < OC) sb2[t] = b2[t];

    int g = t >> 3;
    int qq = t & 3;
    int eh = (t >> 2) & 1;
    int i = blockIdx.x * 32 + g;   // NN = 6250*32 exactly
    unsigned sp = spl[i];
    int c0 = (int)(sp & 255u);
    int c1 = (int)((sp >> 8) & 255u);
    int c2 = (int)((sp >> 16) & 255u);
    int c3 = (int)(sp >> 24);
    int beg = rsg[i] + c0 + c1;    // phases 2+3 are contiguous
    int end = beg + c2 + c3;

    float ax = 0.0f, ay = 0.0f, az = 0.0f, aw = 0.0f;
    int j = beg + eh;
    for (; j + 2 < end; j += 4) {
        int s0 = csr[j];
        int s1 = csr[j + 2];
        uint2 u0 = *(const uint2*)(xph + (size_t)s0 * 16 + 4 * qq);
        uint2 u1 = *(const uint2*)(xph + (size_t)s1 * 16 + 4 * qq);
        float2 f0 = __half22float2(*(__half2*)&u0.x);
        float2 f1 = __half22float2(*(__half2*)&u0.y);
        float2 f2 = __half22float2(*(__half2*)&u1.x);
        float2 f3 = __half22float2(*(__half2*)&u1.y);
        ax += f0.x + f2.x;
        ay += f0.y + f2.y;
        az += f1.x + f3.x;
        aw += f1.y + f3.y;
    }
    if (j < end) {
        int s0 = csr[j];
        uint2 u0 = *(const uint2*)(xph + (size_t)s0 * 16 + 4 * qq);
        float2 f0 = __half22float2(*(__half2*)&u0.x);
        float2 f1 = __half22float2(*(__half2*)&u0.y);
        ax += f0.x;
        ay += f0.y;
        az += f1.x;
        aw += f1.y;
    }

    // partials: eh0 adds buf0 + self row, eh1 adds buf1 (each added once)
    if (eh == 0) {
        f4v a0 = __builtin_nontemporal_load(
            (const f4v*)(partial + (size_t)i * 16 + 4 * qq));
        uint2 us = *(const uint2*)(xph + (size_t)i * 16 + 4 * qq);
        float2 sx = __half22float2(*(__half2*)&us.x);
        float2 sy = __half22float2(*(__half2*)&us.y);
        ax += a0.x + sx.x;
        ay += a0.y + sx.y;
        az += a0.z + sy.x;
        aw += a0.w + sy.y;
    } else {
        f4v a1 = __builtin_nontemporal_load(
            (const f4v*)(partial + ((size_t)NN + i) * 16 + 4 * qq));
        ax += a1.x;
        ay += a1.y;
        az += a1.z;
        aw += a1.w;
    }
    ax += __shfl_xor(ax, 4);
    ay += __shfl_xor(ay, 4);
    az += __shfl_xor(az, 4);
    aw += __shfl_xor(aw, 4);

    float dv = dinv[i];
    if (eh == 0) {
        // overflow fixup (nov==0 in practice)
        int nov = min(gcur[NSEG * GSTR], OVFCAP);
        for (int k = 0; k < nov; ++k) {
            ull e = ovf[k];
            if ((int)(e >> 32) == i) {
                int s = (int)(e & 0xFFFFFFFFu);
                int ch = 4 * qq;
                ax += __half2float(xph[(size_t)s * 16 + ch]);
                ay += __half2float(xph[(size_t)s * 16 + ch + 1]);
                az += __half2float(xph[(size_t)s * 16 + ch + 2]);
                aw += __half2float(xph[(size_t)s * 16 + ch + 3]);
            }
        }
        sAgg[g][4 * qq + 0] = dv * ax;
        sAgg[g][4 * qq + 1] = dv * ay;
        sAgg[g][4 * qq + 2] = dv * az;
        sAgg[g][4 * qq + 3] = dv * aw;
    }
    __syncthreads();

    // MLP: lane l8 = t&7 computes hidden units 2*l8, 2*l8+1 (sAgg row is an
    // LDS broadcast across the node's 8 lanes).
    int l8 = t & 7;
    float o0 = 0.0f, o1 = 0.0f;
#pragma unroll
    for (int f2 = 0; f2 < 2; ++f2) {
        int f = 2 * l8 + f2;
        float a = sb1[f];
#pragma unroll
        for (int c = 0; c < IC; ++c) a = fmaf(sAgg[g][c], sW1[c * HC + f], a);
        a = fmaxf(a, 0.0f);
        o0 = fmaf(a, sW2[f * OC + 0], o0);
        o1 = fmaf(a, sW2[f * OC + 1], o1);
    }
    o0 += __shfl_xor(o0, 1);
    o1 += __shfl_xor(o1, 1);
    o0 += __shfl_xor(o0, 2);
    o1 += __shfl_xor(o1, 2);
    o0 += __shfl_xor(o0, 4);
    o1 += __shfl_xor(o1, 4);
    if (l8 == 0) {
        h2bp[i] = make_float2(o0 * dv, o1 * dv);  // dinv-prescaled for layer 2
        selfout[i] = make_float2(o0 * dv * dv + sb2[0], o1 * dv * dv + sb2[1]);
    }
}

// layer-2: out[i] = selfout[i] + dinv[i] * (sum h2bp[src] + ovf matches).
// 8 lanes per node (stride-8 interleaved walk), 2-way unroll;
// shfl_xor(1,2,4) combine.
__global__ __launch_bounds__(256) void k_agg2(const int* __restrict__ rsg,
                                              const unsigned* __restrict__ spl,
                                              const unsigned* __restrict__ csr,
                                              const int* __restrict__ gcur,
                                              const ull* __restrict__ ovf,
                                              const float* __restrict__ dinv,
                                              const float2* __restrict__ h2bp,
                                              const float2* __restrict__ selfout,
                                              float2* __restrict__ out) {
    int tt = blockIdx.x * 256 + threadIdx.x;
    int i = tt >> 3;
    int h = tt & 7;
    if (i >= NN) return;
    unsigned sp = spl[i];
    int tot = (int)(sp & 255u) + (int)((sp >> 8) & 255u) +
              (int)((sp >> 16) & 255u) + (int)(sp >> 24);
    int beg = rsg[i];
    int end = beg + tot;
    float ax = 0.0f, ay = 0.0f;
    int j = beg + h;
    for (; j + 8 < end; j += 16) {
        int s0 = csr[j];
        int s1 = csr[j + 8];
        float2 h0 = h2bp[s0];
        float2 h1 = h2bp[s1];
        ax += h0.x + h1.x;
        ay += h0.y + h1.y;
    }
    if (j < end) {
        float2 h0 = h2bp[csr[j]];
        ax += h0.x;
        ay += h0.y;
    }
    ax += __shfl_xor(ax, 1);
    ay += __shfl_xor(ay, 1);
    ax += __shfl_xor(ax, 2);
    ay += __shfl_xor(ay, 2);
    ax += __shfl_xor(ax, 4);
    ay += __shfl_xor(ay, 4);
    if (h == 0) {
        // overflow fixup (nov==0 in practice); h2bp already dinv[src]-prescaled
        int nov = min(gcur[NSEG * GSTR], OVFCAP);
        for (int k = 0; k < nov; ++k) {
            ull e = ovf[k];
            if ((int)(e >> 32) == i) {
                float2 hh = h2bp[(int)(e & 0xFFFFFFFFu)];
                ax += hh.x;
                ay += hh.y;
            }
        }
        float dv = dinv[i];
        float2 so = selfout[i];
        out[i] = make_float2(so.x + dv * ax, so.y + dv * ay);
    }
}

extern "C" void kernel_launch(void* const* d_in, const int* in_sizes, int n_in,
                              void* d_out, int out_size, void* d_ws, size_t ws_size,
                              hipStream_t stream) {
    const float* x = (const float*)d_in[0];
    const void* ei = d_in[1];
    // d_in[2] = edge_attr (unused)
    const float* W1 = (const float*)d_in[3];
    const float* b1 = (const float*)d_in[4];
    const float* W2 = (const float*)d_in[5];
    const float* b2 = (const float*)d_in[6];
    float* out = (float*)d_out;

    ull* ovf = (ull*)d_ws;                              // OVFCAP       (0.5MB)
    int* gcur = (int*)(ovf + OVFCAP);                   // (NSEG+5)*16 ints
    int* flag = gcur + (NSEG + 5) * GSTR;               // 4
    int* rsg = flag + 4;                                // NN
    unsigned* spl = (unsigned*)(rsg + NN);              // NN
    float* dinv = (float*)(spl + NN);                   // NN
    __half* xph = (__half*)(dinv + NN);                 // NN*16 halves (6.4MB)
    float2* h2bp = (float2*)(xph + (size_t)NN * 16);    // NN
    float2* selfout = h2bp + NN;                        // NN
    unsigned* binned = (unsigned*)(selfout + NN);       // NSEG*SCAP    (35.3MB)
    float* partial = (float*)binned;                    // 2*NN*16 f32 (25.6MB), overlays
                                                        // binned (dead after k_sort)
    unsigned* csr = binned + (size_t)NSEG * SCAP;       // NBK*CCAP     (35.3MB)

    k_init<<<(NSEG + 5 + 255) / 256, 256, 0, stream>>>(gcur, ei, flag);
    k_binA<<<NTILE, BTH, 0, stream>>>(ei, flag, gcur, binned, ovf);
    k_sort<<<NBK, 1024, 0, stream>>>(gcur, binned, ovf, csr, dinv, rsg, spl);
    k_prep<<<(NN * 16 + 255) / 256, 256, 0, stream>>>(x, dinv, xph);
    k_agg1<<<2 * NM, 256, 0, stream>>>(rsg, spl, csr, xph, partial);
    k_agg1m<<<NM, 256, 0, stream>>>(rsg, spl, csr, xph, partial, gcur, ovf, dinv,
                                    W1, b1, W2, b2, h2bp, selfout);
    k_agg2<<<(NN * 8 + 255) / 256, 256, 0, stream>>>(rsg, spl, csr, gcur, ovf, dinv,
                                                     h2bp, selfout, (float2*)out);
}

// Round 10
// 285.048 us; speedup vs baseline: 1.2425x; 1.0182x over previous
//
#include <hip/hip_runtime.h>
#include <hip/hip_fp16.h>

// GCN 2-layer: N=200000, E=6400000, 14 -> 16(relu) -> 2.
// Round 22: explicit ILP. Profile flat at ~48us x3, all latency-bound;
// binA VGPR=28 proves the compiler issues its 10 edge loads JIT (one
// s_waitcnt vs ~900cy L3 per iteration). agg kernels serialize csr->xph.
//   - binA: preload ALL edge words to static reg buffers before the atomic
//     loop. int64 path loads only the LOW DWORD of each index (1 reg/value)
//     -> ~40 regs of buffer; launch_bounds(512,6).
//   - agg1A/agg1m/agg2: depth-1 software pipeline (load next csr pair before
//     this iteration's gathers; sentinel -1 guards).
// Pipeline: init -> binA -> sort(+dinv) -> prep -> agg1A -> agg1m -> agg2.

constexpr int NN = 200000;
constexpr int NE = 6400000;
constexpr int IC = 14;
constexpr int HC = 16;
constexpr int OC = 2;

constexpr int NBK = 392;                   // buckets of 512 dst nodes
constexpr int NSUB = 8;                    // sub-segments per bucket (= XCD id)
constexpr int SCAP = 2816;                 // per (sub,bucket) cap: mean 2058 + 16.7 sigma
constexpr int NSEG = NSUB * NBK;           // 3136 segments
constexpr int CCAP = NSUB * SCAP;          // 22528 csr per-bucket capacity
constexpr int SPT = (SCAP + 1023) / 1024;  // 3 reg slots per (thread, segment)
constexpr int TILE = 5120;                 // edges per binA tile
constexpr int BTH = 512;                   // binA threads
constexpr int IPT = TILE / BTH;            // 10
constexpr int IPT2 = IPT / 2;              // 5 pair-loads per thread
constexpr int NTILE = NE / TILE;           // 1250
constexpr int OVFCAP = 65536;
constexpr int NM = NN / 32;                // 6250 blocks (32 nodes per block)
constexpr int GSTR = 16;                   // gcur stride: 1 counter per 64B line

typedef unsigned long long ull;
typedef float f4v __attribute__((ext_vector_type(4)));

__device__ __forceinline__ int phase_of(unsigned src) {
    return src >= 100000u ? (src >= 150000u ? 3 : 2) : (src >= 50000u ? 1 : 0);
}

// Physical XCD id (0..7). Affinity heuristic only -- correctness never
// depends on the value (G16): binA has the overflow path.
__device__ __forceinline__ int xcc_id() {
    int x;
    asm volatile("s_getreg_b32 %0, hwreg(HW_REG_XCC_ID)" : "=s"(x));
    return x & 7;
}

// init gcur (padded) + ovf counter + dtype flag
__global__ void k_init(int* __restrict__ gcur, const void* __restrict__ ei,
                       int* __restrict__ flag) {
    int i = blockIdx.x * blockDim.x + threadIdx.x;
    if (i < NSEG) gcur[i * GSTR] = i * SCAP;
    else if (i <= NSEG + 4) gcur[i * GSTR] = 0;  // ovf counter (+spare)
    if (i == 500) {  // one thread sniffs edge dtype
        const ull* p = (const ull*)ei;
        ull acc = 0ULL;
        for (int k = 0; k < 64; ++k) acc |= (p[k] >> 32);
        *flag = (acc == 0ULL) ? 1 : 0;  // 1 => int64 indices, 0 => int32
    }
}

// Bin edges by dst>>9 into per-(sub,bucket) global segments, sub = XCC_ID.
// All edge words preloaded to registers (20 independent loads in flight),
// then the atomic/pack loop runs against warm registers. LDS-staged for
// coalesced segment write-out.
__global__ __launch_bounds__(BTH, 6) void k_binA(const void* __restrict__ ei,
                                                 const int* __restrict__ flag,
                                                 int* __restrict__ gcur,
                                                 unsigned* __restrict__ binned,
                                                 ull* __restrict__ ovf) {
    __shared__ int hist[NBK];
    __shared__ int lofs[NBK];
    __shared__ int gofs[NBK];
    __shared__ int wsum[BTH / 64];
    __shared__ unsigned stage[TILE];

    int t = threadIdx.x;
    int fl = *flag;
    int tile0 = blockIdx.x * TILE;
    int segbase = xcc_id() * NBK;

    if (t < NBK) hist[t] = 0;
    __syncthreads();

    // preload: 20 independent dword loads (int64 path reads low dwords only)
    int dbuf[IPT], sbuf[IPT];
    const int* pw = (const int*)ei;
    if (fl) {
#pragma unroll
        for (int k = 0; k < IPT2; ++k) {
            int e = tile0 + k * (2 * BTH) + 2 * t;
            dbuf[2 * k] = pw[2 * (NE + e)];
            dbuf[2 * k + 1] = pw[2 * (NE + e) + 2];
            sbuf[2 * k] = pw[2 * e];
            sbuf[2 * k + 1] = pw[2 * e + 2];
        }
    } else {
#pragma unroll
        for (int k = 0; k < IPT2; ++k) {
            int e = tile0 + k * (2 * BTH) + 2 * t;
            uint2 dd = *(const uint2*)(pw + NE + e);
            uint2 ss = *(const uint2*)(pw + e);
            dbuf[2 * k] = (int)dd.x;
            dbuf[2 * k + 1] = (int)dd.y;
            sbuf[2 * k] = (int)ss.x;
            sbuf[2 * k + 1] = (int)ss.y;
        }
    }

    // atomic rank capture from registers.
    // pk = (dlow<<18)|src ; ra = (rank<<9)|bucket  (rank<5120 fits 13 bits)
    unsigned pk[IPT];
    unsigned ra[IPT];
#pragma unroll
    for (int k = 0; k < IPT; ++k) {
        int d = dbuf[k];
        int b = d >> 9;
        int r = atomicAdd(&hist[b], 1);
        pk[k] = ((unsigned)(d & 511) << 18) | (unsigned)sbuf[k];
        ra[k] = ((unsigned)r << 9) | (unsigned)b;
    }
    __syncthreads();

    // exclusive scan of 392 counts: pair-sum + 64-lane shfl scan + wave combine
    int h0 = 0, h1 = 0, p = 0;
    if (t < NBK / 2) {
        h0 = hist[2 * t];
        h1 = hist[2 * t + 1];
        p = h0 + h1;
    }
    int lane = t & 63;
    int w = t >> 6;
    int incl = p;
#pragma unroll
    for (int off = 1; off < 64; off <<= 1) {
        int v = __shfl_up(incl, off, 64);
        if (lane >= off) incl += v;
    }
    if (lane == 63) wsum[w] = incl;
    __syncthreads();
    int wbase = 0;
#pragma unroll
    for (int ww = 0; ww < BTH / 64; ++ww) wbase += (ww < w) ? wsum[ww] : 0;
    int ex = wbase + incl - p;
    if (t < NBK / 2) {
        lofs[2 * t] = ex;
        lofs[2 * t + 1] = ex + h0;
    }
    if (t < NBK) gofs[t] = atomicAdd(&gcur[(segbase + t) * GSTR], hist[t]);
    __syncthreads();

    // stage from regs at lofs[bucket] + rank (no global loads)
#pragma unroll
    for (int k = 0; k < IPT; ++k) {
        int b = (int)(ra[k] & 511u);
        int r = (int)(ra[k] >> 9);
        stage[lofs[b] + r] = pk[k];
    }
    __syncthreads();

    // coalesced write-out; bucket of slot i via seeded search on lofs
    for (int i = t; i < TILE; i += BTH) {
        int b = (i * 313) >> 12;  // ~ i / 13.06 (mean slots per bucket)
        if (b > NBK - 1) b = NBK - 1;
        while (b < NBK - 1 && lofs[b + 1] <= i) ++b;
        while (lofs[b] > i) --b;
        unsigned pack = stage[i];
        int seg = segbase + b;
        int dest = gofs[b] + (i - lofs[b]);
        if (dest < (seg + 1) * SCAP) {
            binned[dest] = pack;
        } else {  // overflow (never in practice)
            int op = atomicAdd(&gcur[NSEG * GSTR], 1);
            if (op < OVFCAP) {
                int d = (b << 9) | (int)(pack >> 18);
                int s = (int)(pack & 0x3FFFF);
                ovf[op] = ((ull)d << 32) | (unsigned)s;
            }
        }
    }
}

// bucket-local counting sort over 8 sub-segments, key = (dlow<<2)|phase(src).
// Single pass: rank captured from cnt atomic, (src, rank|key) in regs
// (static 8x3 slots); scatter into LDS stage at excl[key]+rank; coalesced
// uint4 write-out (every csr line written once -> no write amplification).
// Also computes dinv = rsqrt(degree+1) and packs 4x8-bit phase counts.
__global__ __launch_bounds__(1024, 4) void k_sort(const int* __restrict__ gcur,
                                                  const unsigned* __restrict__ binned,
                                                  const ull* __restrict__ ovf,
                                                  unsigned* __restrict__ csr,
                                                  float* __restrict__ dinv,
                                                  int* __restrict__ rsg,
                                                  unsigned* __restrict__ spl) {
    __shared__ int cnt[2048];
    __shared__ int excl[2048];
    __shared__ int wsum[16];
    __shared__ int nseg[NSUB];
    __shared__ unsigned stage[CCAP];      // 88KB sorted bucket staging
    int b = blockIdx.x;
    int t = threadIdx.x;
    cnt[t] = 0;
    cnt[t + 1024] = 0;
    if (t < NSUB) {
        int seg = t * NBK + b;
        nseg[t] = min(gcur[seg * GSTR] - seg * SCAP, SCAP);
    }
    __syncthreads();
    int nov = min(gcur[NSEG * GSTR], OVFCAP);

    // single pass: load + key + rank capture; held in regs (static indexing)
    unsigned srcv[NSUB * SPT];
    unsigned rkv[NSUB * SPT];
#pragma unroll
    for (int s = 0; s < NSUB; ++s) {
        int n = nseg[s];
        int sb = (s * NBK + b) * SCAP;
#pragma unroll
        for (int k = 0; k < SPT; ++k) {
            int i = k * 1024 + t;
            rkv[s * SPT + k] = 0xFFFFFFFFu;
            if (i < n) {
                unsigned pack = binned[sb + i];
                unsigned src = pack & 0x3FFFFu;
                int key = ((int)(pack >> 18) << 2) | phase_of(src);
                int r = atomicAdd(&cnt[key], 1);
                srcv[s * SPT + k] = src;
                rkv[s * SPT + k] = ((unsigned)r << 11) | (unsigned)key;
            }
        }
    }
    __syncthreads();

    // exclusive scan of 2048 counts: pair-sum + 1024-lane scan (16 waves)
    int h0 = cnt[2 * t];
    int h1 = cnt[2 * t + 1];
    int p = h0 + h1;
    int lane = t & 63;
    int w = t >> 6;
    int incl = p;
#pragma unroll
    for (int off = 1; off < 64; off <<= 1) {
        int v = __shfl_up(incl, off, 64);
        if (lane >= off) incl += v;
    }
    if (lane == 63) wsum[w] = incl;
    __syncthreads();
    int wbase = 0;
#pragma unroll
    for (int ww = 0; ww < 16; ++ww) wbase += (ww < w) ? wsum[ww] : 0;
    int ex = wbase + incl - p;
    excl[2 * t] = ex;
    excl[2 * t + 1] = ex + h0;
    __syncthreads();

    // scatter into LDS stage (bucket-relative positions)
#pragma unroll
    for (int c = 0; c < NSUB * SPT; ++c) {
        unsigned rk = rkv[c];
        if (rk != 0xFFFFFFFFu) {
            int key = (int)(rk & 0x7FFu);
            int r = (int)(rk >> 11);
            stage[excl[key] + r] = srcv[c];
        }
    }

    // per-node stats (cnt/excl are stable; independent of stage)
    if (t < 512) {
        int g = (b << 9) + t;
        if (g < NN) {
            int c0 = cnt[4 * t];
            int c1 = cnt[4 * t + 1];
            int c2 = cnt[4 * t + 2];
            int c3 = cnt[4 * t + 3];
            int extra = 0;
            for (int k = 0; k < nov; ++k) extra += ((int)(ovf[k] >> 32) == g);
            dinv[g] = rsqrtf((float)(c0 + c1 + c2 + c3 + extra) + 1.0f);
            rsg[g] = b * CCAP + excl[4 * t];                 // csr row start (absolute)
            spl[g] = (unsigned)c0 | ((unsigned)c1 << 8) |
                     ((unsigned)c2 << 16) | ((unsigned)c3 << 24);
        }
    }
    __syncthreads();

    // coalesced uint4 write-out (pad to 16B; garbage pad stays in-bucket)
    int total = excl[2047] + cnt[2047];
    int tot4 = (total + 3) >> 2;
    const uint4* st4 = (const uint4*)stage;
    uint4* csr4 = (uint4*)(csr + (size_t)b * CCAP);
#pragma unroll
    for (int k = 0; k < (CCAP / 4 + 1023) / 1024; ++k) {
        int i4 = k * 1024 + t;
        if (i4 < tot4) csr4[i4] = st4[i4];
    }
}

// xph[s] = fp16(dinv[s]*x[s]) padded to 16 halves (one aligned 32B row).
__global__ void k_prep(const float* __restrict__ x, const float* __restrict__ dinv,
                       __half* __restrict__ xph) {
    int i = blockIdx.x * blockDim.x + threadIdx.x;
    if (i >= NN * 16) return;
    int node = i >> 4;
    int c = i & 15;
    float v = (c < IC) ? dinv[node] * x[node * IC + c] : 0.0f;
    xph[i] = __float2half(v);
}

// Layer-1 aggregation launch A: phases {0,1}, q2 = bid&1. 8 lanes per node
// (qq channel slice x eh edge half). Depth-1 software pipeline: next csr
// pair loads issue BEFORE this iteration's xph gathers (sentinel -1).
__global__ __launch_bounds__(256) void k_agg1(const int* __restrict__ rsg,
                                              const unsigned* __restrict__ spl,
                                              const unsigned* __restrict__ csr,
                                              const __half* __restrict__ xph,
                                              float* __restrict__ partial) {
    int t = threadIdx.x;
    int q2 = blockIdx.x & 1;
    int blk = blockIdx.x >> 1;
    int g = t >> 3;
    int qq = t & 3;
    int eh = (t >> 2) & 1;
    int i = blk * 32 + g;
    unsigned sp = spl[i];
    int c0 = (int)(sp & 255u);
    int c1 = (int)((sp >> 8) & 255u);
    int beg = rsg[i] + (q2 ? c0 : 0);
    int end = beg + (q2 ? c1 : c0);

    float ax = 0.0f, ay = 0.0f, az = 0.0f, aw = 0.0f;
    int j = beg + eh;
    int s0 = (j < end) ? (int)csr[j] : -1;
    int s1 = (j + 2 < end) ? (int)csr[j + 2] : -1;
    while (j < end) {
        int jn = j + 4;
        int n0 = (jn < end) ? (int)csr[jn] : -1;
        int n1 = (jn + 2 < end) ? (int)csr[jn + 2] : -1;
        uint2 u0 = *(const uint2*)(xph + (size_t)s0 * 16 + 4 * qq);
        float2 f0 = __half22float2(*(__half2*)&u0.x);
        float2 f1 = __half22float2(*(__half2*)&u0.y);
        ax += f0.x;
        ay += f0.y;
        az += f1.x;
        aw += f1.y;
        if (s1 >= 0) {
            uint2 u1 = *(const uint2*)(xph + (size_t)s1 * 16 + 4 * qq);
            float2 f2 = __half22float2(*(__half2*)&u1.x);
            float2 f3 = __half22float2(*(__half2*)&u1.y);
            ax += f2.x;
            ay += f2.y;
            az += f3.x;
            aw += f3.y;
        }
        s0 = n0;
        s1 = n1;
        j = jn;
    }
    ax += __shfl_xor(ax, 4);
    ay += __shfl_xor(ay, 4);
    az += __shfl_xor(az, 4);
    aw += __shfl_xor(aw, 4);
    if (eh == 0) {
        f4v r = {ax, ay, az, aw};
        __builtin_nontemporal_store(
            r, (f4v*)(partial + ((size_t)q2 * NN + i) * 16 + 4 * qq));
    }
}

// Launch B: phases {2,3} (contiguous csr range) + partial nt-read + self-loop
// + overflow fixup + fused MLP. 8 lanes per node; depth-1 csr pipeline;
// shfl_xor(4) combines halves; padded LDS tile exchanges agg; 2 hidden units
// per lane, shfl_xor(1,2,4) combines the output dot. Writes h2bp/selfout.
__global__ __launch_bounds__(256) void k_agg1m(const int* __restrict__ rsg,
                                               const unsigned* __restrict__ spl,
                                               const unsigned* __restrict__ csr,
                                               const __half* __restrict__ xph,
                                               const float* __restrict__ partial,
                                               const int* __restrict__ gcur,
                                               const ull* __restrict__ ovf,
                                               const float* __restrict__ dinv,
                                               const float* __restrict__ W1,
                                               const float* __restrict__ b1,
                                               const float* __restrict__ W2,
                                               const float* __restrict__ b2,
                                               float2* __restrict__ h2bp,
                                               float2* __restrict__ selfout) {
    __shared__ float sW1[IC * HC];
    __shared__ float sb1[HC];
    __shared__ float sW2[HC * OC];
    __shared__ float sb2[OC];
    __shared__ float sAgg[32][17];  // +1 pad: spread rows across banks
    int t = threadIdx.x;
    if (t < IC * HC) sW1[t] = W1[t];
    if (t < HC) sb1[t] = b1[t];
    if (t < HC * OC) sW2[t] = W2[t];
    if (t < OC) sb2[t] = b2[t];

    int g = t >> 3;
    int qq = t & 3;
    int eh = (t >> 2) & 1;
    int i = blockIdx.x * 32 + g;   // NN = 6250*32 exactly
    unsigned sp = spl[i];
    int c0 = (int)(sp & 255u);
    int c1 = (int)((sp >> 8) & 255u);
    int c2 = (int)((sp >> 16) & 255u);
    int c3 = (int)(sp >> 24);
    int beg = rsg[i] + c0 + c1;    // phases 2+3 are contiguous
    int end = beg + c2 + c3;

    float ax = 0.0f, ay = 0.0f, az = 0.0f, aw = 0.0f;
    int j = beg + eh;
    int s0 = (j < end) ? (int)csr[j] : -1;
    int s1 = (j + 2 < end) ? (int)csr[j + 2] : -1;
    while (j < end) {
        int jn = j + 4;
        int n0 = (jn < end) ? (int)csr[jn] : -1;
        int n1 = (jn + 2 < end) ? (int)csr[jn + 2] : -1;
        uint2 u0 = *(const uint2*)(xph + (size_t)s0 * 16 + 4 * qq);
        float2 f0 = __half22float2(*(__half2*)&u0.x);
        float2 f1 = __half22float2(*(__half2*)&u0.y);
        ax += f0.x;
        ay += f0.y;
        az += f1.x;
        aw += f1.y;
        if (s1 >= 0) {
            uint2 u1 = *(const uint2*)(xph + (size_t)s1 * 16 + 4 * qq);
            float2 f2 = __half22float2(*(__half2*)&u1.x);
            float2 f3 = __half22float2(*(__half2*)&u1.y);
            ax += f2.x;
            ay += f2.y;
            az += f3.x;
            aw += f3.y;
        }
        s0 = n0;
        s1 = n1;
        j = jn;
    }

    // partials: eh0 adds buf0 + self row, eh1 adds buf1 (each added once)
    if (eh == 0) {
        f4v a0 = __builtin_nontemporal_load(
            (const f4v*)(partial + (size_t)i * 16 + 4 * qq));
        uint2 us = *(const uint2*)(xph + (size_t)i * 16 + 4 * qq);
        float2 sx = __half22float2(*(__half2*)&us.x);
        float2 sy = __half22float2(*(__half2*)&us.y);
        ax += a0.x + sx.x;
        ay += a0.y + sx.y;
        az += a0.z + sy.x;
        aw += a0.w + sy.y;
    } else {
        f4v a1 = __builtin_nontemporal_load(
            (const f4v*)(partial + ((size_t)NN + i) * 16 + 4 * qq));
        ax += a1.x;
        ay += a1.y;
        az += a1.z;
        aw += a1.w;
    }
    ax += __shfl_xor(ax, 4);
    ay += __shfl_xor(ay, 4);
    az += __shfl_xor(az, 4);
    aw += __shfl_xor(aw, 4);

    float dv = dinv[i];
    if (eh == 0) {
        // overflow fixup (nov==0 in practice)
        int nov = min(gcur[NSEG * GSTR], OVFCAP);
        for (int k = 0; k < nov; ++k) {
            ull e = ovf[k];
            if ((int)(e >> 32) == i) {
                int s = (int)(e & 0xFFFFFFFFu);
                int ch = 4 * qq;
                ax += __half2float(xph[(size_t)s * 16 + ch]);
                ay += __half2float(xph[(size_t)s * 16 + ch + 1]);
                az += __half2float(xph[(size_t)s * 16 + ch + 2]);
                aw += __half2float(xph[(size_t)s * 16 + ch + 3]);
            }
        }
        sAgg[g][4 * qq + 0] = dv * ax;
        sAgg[g][4 * qq + 1] = dv * ay;
        sAgg[g][4 * qq + 2] = dv * az;
        sAgg[g][4 * qq + 3] = dv * aw;
    }
    __syncthreads();

    // MLP: lane l8 = t&7 computes hidden units 2*l8, 2*l8+1 (sAgg row is an
    // LDS broadcast across the node's 8 lanes).
    int l8 = t & 7;
    float o0 = 0.0f, o1 = 0.0f;
#pragma unroll
    for (int f2 = 0; f2 < 2; ++f2) {
        int f = 2 * l8 + f2;
        float a = sb1[f];
#pragma unroll
        for (int c = 0; c < IC; ++c) a = fmaf(sAgg[g][c], sW1[c * HC + f], a);
        a = fmaxf(a, 0.0f);
        o0 = fmaf(a, sW2[f * OC + 0], o0);
        o1 = fmaf(a, sW2[f * OC + 1], o1);
    }
    o0 += __shfl_xor(o0, 1);
    o1 += __shfl_xor(o1, 1);
    o0 += __shfl_xor(o0, 2);
    o1 += __shfl_xor(o1, 2);
    o0 += __shfl_xor(o0, 4);
    o1 += __shfl_xor(o1, 4);
    if (l8 == 0) {
        h2bp[i] = make_float2(o0 * dv, o1 * dv);  // dinv-prescaled for layer 2
        selfout[i] = make_float2(o0 * dv * dv + sb2[0], o1 * dv * dv + sb2[1]);
    }
}

// layer-2: out[i] = selfout[i] + dinv[i] * (sum h2bp[src] + ovf matches).
// 8 lanes per node, depth-1 csr pipeline; shfl_xor(1,2,4) combine.
__global__ __launch_bounds__(256) void k_agg2(const int* __restrict__ rsg,
                                              const unsigned* __restrict__ spl,
                                              const unsigned* __restrict__ csr,
                                              const int* __restrict__ gcur,
                                              const ull* __restrict__ ovf,
                                              const float* __restrict__ dinv,
                                              const float2* __restrict__ h2bp,
                                              const float2* __restrict__ selfout,
                                              float2* __restrict__ out) {
    int tt = blockIdx.x * 256 + threadIdx.x;
    int i = tt >> 3;
    int h = tt & 7;
    if (i >= NN) return;
    unsigned sp = spl[i];
    int tot = (int)(sp & 255u) + (int)((sp >> 8) & 255u) +
              (int)((sp >> 16) & 255u) + (int)(sp >> 24);
    int beg = rsg[i];
    int end = beg + tot;
    float ax = 0.0f, ay = 0.0f;
    int j = beg + h;
    int s0 = (j < end) ? (int)csr[j] : -1;
    int s1 = (j + 8 < end) ? (int)csr[j + 8] : -1;
    while (j < end) {
        int jn = j + 16;
        int n0 = (jn < end) ? (int)csr[jn] : -1;
        int n1 = (jn + 8 < end) ? (int)csr[jn + 8] : -1;
        float2 h0 = h2bp[s0];
        ax += h0.x;
        ay += h0.y;
        if (s1 >= 0) {
            float2 h1 = h2bp[s1];
            ax += h1.x;
            ay += h1.y;
        }
        s0 = n0;
        s1 = n1;
        j = jn;
    }
    ax += __shfl_xor(ax, 1);
    ay += __shfl_xor(ay, 1);
    ax += __shfl_xor(ax, 2);
    ay += __shfl_xor(ay, 2);
    ax += __shfl_xor(ax, 4);
    ay += __shfl_xor(ay, 4);
    if (h == 0) {
        // overflow fixup (nov==0 in practice); h2bp already dinv[src]-prescaled
        int nov = min(gcur[NSEG * GSTR], OVFCAP);
        for (int k = 0; k < nov; ++k) {
            ull e = ovf[k];
            if ((int)(e >> 32) == i) {
                float2 hh = h2bp[(int)(e & 0xFFFFFFFFu)];
                ax += hh.x;
                ay += hh.y;
            }
        }
        float dv = dinv[i];
        float2 so = selfout[i];
        out[i] = make_float2(so.x + dv * ax, so.y + dv * ay);
    }
}

extern "C" void kernel_launch(void* const* d_in, const int* in_sizes, int n_in,
                              void* d_out, int out_size, void* d_ws, size_t ws_size,
                              hipStream_t stream) {
    const float* x = (const float*)d_in[0];
    const void* ei = d_in[1];
    // d_in[2] = edge_attr (unused)
    const float* W1 = (const float*)d_in[3];
    const float* b1 = (const float*)d_in[4];
    const float* W2 = (const float*)d_in[5];
    const float* b2 = (const float*)d_in[6];
    float* out = (float*)d_out;

    ull* ovf = (ull*)d_ws;                              // OVFCAP       (0.5MB)
    int* gcur = (int*)(ovf + OVFCAP);                   // (NSEG+5)*16 ints
    int* flag = gcur + (NSEG + 5) * GSTR;               // 4
    int* rsg = flag + 4;                                // NN
    unsigned* spl = (unsigned*)(rsg + NN);              // NN
    float* dinv = (float*)(spl + NN);                   // NN
    __half* xph = (__half*)(dinv + NN);                 // NN*16 halves (6.4MB)
    float2* h2bp = (float2*)(xph + (size_t)NN * 16);    // NN
    float2* selfout = h2bp + NN;                        // NN
    unsigned* binned = (unsigned*)(selfout + NN);       // NSEG*SCAP    (35.3MB)
    float* partial = (float*)binned;                    // 2*NN*16 f32 (25.6MB), overlays
                                                        // binned (dead after k_sort)
    unsigned* csr = binned + (size_t)NSEG * SCAP;       // NBK*CCAP     (35.3MB)

    k_init<<<(NSEG + 5 + 255) / 256, 256, 0, stream>>>(gcur, ei, flag);
    k_binA<<<NTILE, BTH, 0, stream>>>(ei, flag, gcur, binned, ovf);
    k_sort<<<NBK, 1024, 0, stream>>>(gcur, binned, ovf, csr, dinv, rsg, spl);
    k_prep<<<(NN * 16 + 255) / 256, 256, 0, stream>>>(x, dinv, xph);
    k_agg1<<<2 * NM, 256, 0, stream>>>(rsg, spl, csr, xph, partial);
    k_agg1m<<<NM, 256, 0, stream>>>(rsg, spl, csr, xph, partial, gcur, ovf, dinv,
                                    W1, b1, W2, b2, h2bp, selfout);
    k_agg2<<<(NN * 8 + 255) / 256, 256, 0, stream>>>(rsg, spl, csr, gcur, ovf, dinv,
                                                     h2bp, selfout, (float2*)out);
}

// Round 11
// 271.594 us; speedup vs baseline: 1.3040x; 1.0495x over previous
//
#include <hip/hip_runtime.h>
#include <hip/hip_fp16.h>

// GCN 2-layer: N=200000, E=6400000, 14 -> 16(relu) -> 2.
// Round 23: halve gather requests + delete k_prep.
//   - agg1A/agg1m lanes re-sliced: qc = channel HALF (16B uint4 gather) x
//     eh = edge quarter. Per edge: 2x16B requests instead of 4x8B -- same
//     bytes, half the L2 transactions, same 8-deep load parallelism.
//     Partial bufs + self row folded in pre-combine (eh0: buf0+self,
//     eh1: buf1), summed by the existing shfl_xor(2,4) tree.
//   - k_prep fused into k_sort: block b owns nodes [b*512,b*512+512);
//     stats stashes dinv in LDS; after csr write-out, 2 threads/node write
//     the xph row (float2 loads, half2 packs, uint4 store). One launch and
//     the dinv re-read deleted.
// Pipeline: init -> binA -> sort(+dinv+xph) -> agg1A -> agg1m -> agg2.

constexpr int NN = 200000;
constexpr int NE = 6400000;
constexpr int IC = 14;
constexpr int HC = 16;
constexpr int OC = 2;

constexpr int NBK = 392;                   // buckets of 512 dst nodes
constexpr int NSUB = 8;                    // sub-segments per bucket (= XCD id)
constexpr int SCAP = 2816;                 // per (sub,bucket) cap: mean 2058 + 16.7 sigma
constexpr int NSEG = NSUB * NBK;           // 3136 segments
constexpr int CCAP = NSUB * SCAP;          // 22528 csr per-bucket capacity
constexpr int SPT = (SCAP + 1023) / 1024;  // 3 reg slots per (thread, segment)
constexpr int TILE = 5120;                 // edges per binA tile
constexpr int BTH = 512;                   // binA threads
constexpr int IPT = TILE / BTH;            // 10
constexpr int IPT2 = IPT / 2;              // 5 pair-loads per thread
constexpr int NTILE = NE / TILE;           // 1250
constexpr int OVFCAP = 65536;
constexpr int NM = NN / 32;                // 6250 blocks (32 nodes per block)
constexpr int GSTR = 16;                   // gcur stride: 1 counter per 64B line

typedef unsigned long long ull;
typedef float f4v __attribute__((ext_vector_type(4)));

__device__ __forceinline__ int phase_of(unsigned src) {
    return src >= 100000u ? (src >= 150000u ? 3 : 2) : (src >= 50000u ? 1 : 0);
}

// Physical XCD id (0..7). Affinity heuristic only -- correctness never
// depends on the value (G16): binA has the overflow path.
__device__ __forceinline__ int xcc_id() {
    int x;
    asm volatile("s_getreg_b32 %0, hwreg(HW_REG_XCC_ID)" : "=s"(x));
    return x & 7;
}

// accumulate 8 halves (one 16B xph half-row) into av[8]
__device__ __forceinline__ void acc8(float* av, uint4 u) {
    float2 f0 = __half22float2(*(__half2*)&u.x);
    float2 f1 = __half22float2(*(__half2*)&u.y);
    float2 f2 = __half22float2(*(__half2*)&u.z);
    float2 f3 = __half22float2(*(__half2*)&u.w);
    av[0] += f0.x; av[1] += f0.y; av[2] += f1.x; av[3] += f1.y;
    av[4] += f2.x; av[5] += f2.y; av[6] += f3.x; av[7] += f3.y;
}

// init gcur (padded) + ovf counter + dtype flag
__global__ void k_init(int* __restrict__ gcur, const void* __restrict__ ei,
                       int* __restrict__ flag) {
    int i = blockIdx.x * blockDim.x + threadIdx.x;
    if (i < NSEG) gcur[i * GSTR] = i * SCAP;
    else if (i <= NSEG + 4) gcur[i * GSTR] = 0;  // ovf counter (+spare)
    if (i == 500) {  // one thread sniffs edge dtype
        const ull* p = (const ull*)ei;
        ull acc = 0ULL;
        for (int k = 0; k < 64; ++k) acc |= (p[k] >> 32);
        *flag = (acc == 0ULL) ? 1 : 0;  // 1 => int64 indices, 0 => int32
    }
}

// Bin edges by dst>>9 into per-(sub,bucket) global segments, sub = XCC_ID.
// All edge words preloaded to registers (20 independent loads in flight),
// then the atomic/pack loop runs against warm registers. LDS-staged for
// coalesced segment write-out.
__global__ __launch_bounds__(BTH, 6) void k_binA(const void* __restrict__ ei,
                                                 const int* __restrict__ flag,
                                                 int* __restrict__ gcur,
                                                 unsigned* __restrict__ binned,
                                                 ull* __restrict__ ovf) {
    __shared__ int hist[NBK];
    __shared__ int lofs[NBK];
    __shared__ int gofs[NBK];
    __shared__ int wsum[BTH / 64];
    __shared__ unsigned stage[TILE];

    int t = threadIdx.x;
    int fl = *flag;
    int tile0 = blockIdx.x * TILE;
    int segbase = xcc_id() * NBK;

    if (t < NBK) hist[t] = 0;
    __syncthreads();

    // preload: 20 independent dword loads (int64 path reads low dwords only)
    int dbuf[IPT], sbuf[IPT];
    const int* pw = (const int*)ei;
    if (fl) {
#pragma unroll
        for (int k = 0; k < IPT2; ++k) {
            int e = tile0 + k * (2 * BTH) + 2 * t;
            dbuf[2 * k] = pw[2 * (NE + e)];
            dbuf[2 * k + 1] = pw[2 * (NE + e) + 2];
            sbuf[2 * k] = pw[2 * e];
            sbuf[2 * k + 1] = pw[2 * e + 2];
        }
    } else {
#pragma unroll
        for (int k = 0; k < IPT2; ++k) {
            int e = tile0 + k * (2 * BTH) + 2 * t;
            uint2 dd = *(const uint2*)(pw + NE + e);
            uint2 ss = *(const uint2*)(pw + e);
            dbuf[2 * k] = (int)dd.x;
            dbuf[2 * k + 1] = (int)dd.y;
            sbuf[2 * k] = (int)ss.x;
            sbuf[2 * k + 1] = (int)ss.y;
        }
    }

    // atomic rank capture from registers.
    // pk = (dlow<<18)|src ; ra = (rank<<9)|bucket  (rank<5120 fits 13 bits)
    unsigned pk[IPT];
    unsigned ra[IPT];
#pragma unroll
    for (int k = 0; k < IPT; ++k) {
        int d = dbuf[k];
        int b = d >> 9;
        int r = atomicAdd(&hist[b], 1);
        pk[k] = ((unsigned)(d & 511) << 18) | (unsigned)sbuf[k];
        ra[k] = ((unsigned)r << 9) | (unsigned)b;
    }
    __syncthreads();

    // exclusive scan of 392 counts: pair-sum + 64-lane shfl scan + wave combine
    int h0 = 0, h1 = 0, p = 0;
    if (t < NBK / 2) {
        h0 = hist[2 * t];
        h1 = hist[2 * t + 1];
        p = h0 + h1;
    }
    int lane = t & 63;
    int w = t >> 6;
    int incl = p;
#pragma unroll
    for (int off = 1; off < 64; off <<= 1) {
        int v = __shfl_up(incl, off, 64);
        if (lane >= off) incl += v;
    }
    if (lane == 63) wsum[w] = incl;
    __syncthreads();
    int wbase = 0;
#pragma unroll
    for (int ww = 0; ww < BTH / 64; ++ww) wbase += (ww < w) ? wsum[ww] : 0;
    int ex = wbase + incl - p;
    if (t < NBK / 2) {
        lofs[2 * t] = ex;
        lofs[2 * t + 1] = ex + h0;
    }
    if (t < NBK) gofs[t] = atomicAdd(&gcur[(segbase + t) * GSTR], hist[t]);
    __syncthreads();

    // stage from regs at lofs[bucket] + rank (no global loads)
#pragma unroll
    for (int k = 0; k < IPT; ++k) {
        int b = (int)(ra[k] & 511u);
        int r = (int)(ra[k] >> 9);
        stage[lofs[b] + r] = pk[k];
    }
    __syncthreads();

    // coalesced write-out; bucket of slot i via seeded search on lofs
    for (int i = t; i < TILE; i += BTH) {
        int b = (i * 313) >> 12;  // ~ i / 13.06 (mean slots per bucket)
        if (b > NBK - 1) b = NBK - 1;
        while (b < NBK - 1 && lofs[b + 1] <= i) ++b;
        while (lofs[b] > i) --b;
        unsigned pack = stage[i];
        int seg = segbase + b;
        int dest = gofs[b] + (i - lofs[b]);
        if (dest < (seg + 1) * SCAP) {
            binned[dest] = pack;
        } else {  // overflow (never in practice)
            int op = atomicAdd(&gcur[NSEG * GSTR], 1);
            if (op < OVFCAP) {
                int d = (b << 9) | (int)(pack >> 18);
                int s = (int)(pack & 0x3FFFF);
                ovf[op] = ((ull)d << 32) | (unsigned)s;
            }
        }
    }
}

// bucket-local counting sort over 8 sub-segments, key = (dlow<<2)|phase(src).
// Single pass: rank captured from cnt atomic, (src, rank|key) in regs;
// scatter into LDS stage; coalesced uint4 write-out. Computes dinv and packed
// phase counts. NEW: fused prep -- after write-out, 2 threads/node write the
// block's 512 xph rows (fp16 dinv*x, padded to 16 halves).
__global__ __launch_bounds__(1024, 4) void k_sort(const int* __restrict__ gcur,
                                                  const unsigned* __restrict__ binned,
                                                  const ull* __restrict__ ovf,
                                                  const float* __restrict__ x,
                                                  unsigned* __restrict__ csr,
                                                  float* __restrict__ dinv,
                                                  int* __restrict__ rsg,
                                                  unsigned* __restrict__ spl,
                                                  __half* __restrict__ xph) {
    __shared__ int cnt[2048];
    __shared__ int excl[2048];
    __shared__ int wsum[16];
    __shared__ int nseg[NSUB];
    __shared__ float sdv[512];
    __shared__ unsigned stage[CCAP];      // 88KB sorted bucket staging
    int b = blockIdx.x;
    int t = threadIdx.x;
    cnt[t] = 0;
    cnt[t + 1024] = 0;
    if (t < NSUB) {
        int seg = t * NBK + b;
        nseg[t] = min(gcur[seg * GSTR] - seg * SCAP, SCAP);
    }
    __syncthreads();
    int nov = min(gcur[NSEG * GSTR], OVFCAP);

    // single pass: load + key + rank capture; held in regs (static indexing)
    unsigned srcv[NSUB * SPT];
    unsigned rkv[NSUB * SPT];
#pragma unroll
    for (int s = 0; s < NSUB; ++s) {
        int n = nseg[s];
        int sb = (s * NBK + b) * SCAP;
#pragma unroll
        for (int k = 0; k < SPT; ++k) {
            int i = k * 1024 + t;
            rkv[s * SPT + k] = 0xFFFFFFFFu;
            if (i < n) {
                unsigned pack = binned[sb + i];
                unsigned src = pack & 0x3FFFFu;
                int key = ((int)(pack >> 18) << 2) | phase_of(src);
                int r = atomicAdd(&cnt[key], 1);
                srcv[s * SPT + k] = src;
                rkv[s * SPT + k] = ((unsigned)r << 11) | (unsigned)key;
            }
        }
    }
    __syncthreads();

    // exclusive scan of 2048 counts: pair-sum + 1024-lane scan (16 waves)
    int h0 = cnt[2 * t];
    int h1 = cnt[2 * t + 1];
    int p = h0 + h1;
    int lane = t & 63;
    int w = t >> 6;
    int incl = p;
#pragma unroll
    for (int off = 1; off < 64; off <<= 1) {
        int v = __shfl_up(incl, off, 64);
        if (lane >= off) incl += v;
    }
    if (lane == 63) wsum[w] = incl;
    __syncthreads();
    int wbase = 0;
#pragma unroll
    for (int ww = 0; ww < 16; ++ww) wbase += (ww < w) ? wsum[ww] : 0;
    int ex = wbase + incl - p;
    excl[2 * t] = ex;
    excl[2 * t + 1] = ex + h0;
    __syncthreads();

    // scatter into LDS stage (bucket-relative positions)
#pragma unroll
    for (int c = 0; c < NSUB * SPT; ++c) {
        unsigned rk = rkv[c];
        if (rk != 0xFFFFFFFFu) {
            int key = (int)(rk & 0x7FFu);
            int r = (int)(rk >> 11);
            stage[excl[key] + r] = srcv[c];
        }
    }

    // per-node stats (cnt/excl are stable; independent of stage)
    if (t < 512) {
        int g = (b << 9) + t;
        if (g < NN) {
            int c0 = cnt[4 * t];
            int c1 = cnt[4 * t + 1];
            int c2 = cnt[4 * t + 2];
            int c3 = cnt[4 * t + 3];
            int extra = 0;
            for (int k = 0; k < nov; ++k) extra += ((int)(ovf[k] >> 32) == g);
            float dv = rsqrtf((float)(c0 + c1 + c2 + c3 + extra) + 1.0f);
            dinv[g] = dv;
            sdv[t] = dv;
            rsg[g] = b * CCAP + excl[4 * t];                 // csr row start (absolute)
            spl[g] = (unsigned)c0 | ((unsigned)c1 << 8) |
                     ((unsigned)c2 << 16) | ((unsigned)c3 << 24);
        }
    }
    __syncthreads();

    // coalesced uint4 write-out (pad to 16B; garbage pad stays in-bucket)
    int total = excl[2047] + cnt[2047];
    int tot4 = (total + 3) >> 2;
    const uint4* st4 = (const uint4*)stage;
    uint4* csr4 = (uint4*)(csr + (size_t)b * CCAP);
#pragma unroll
    for (int k = 0; k < (CCAP / 4 + 1023) / 1024; ++k) {
        int i4 = k * 1024 + t;
        if (i4 < tot4) csr4[i4] = st4[i4];
    }

    // fused prep: xph rows for this block's 512 nodes (2 threads per node,
    // 8 halves each). sdv synced by the pre-write-out barrier.
    {
        int n512 = t >> 1;
        int g = (b << 9) + n512;
        if (g < NN) {
            float dv = sdv[n512];
            int cb = 8 * (t & 1);
            const float* xr = x + (size_t)g * IC;
            float v[8];
#pragma unroll
            for (int c = 0; c < 8; c += 2) {
                int ch = cb + c;
                if (ch + 1 < IC) {
                    float2 xx = *(const float2*)(xr + ch);
                    v[c] = dv * xx.x;
                    v[c + 1] = dv * xx.y;
                } else {
                    v[c] = 0.0f;
                    v[c + 1] = 0.0f;
                }
            }
            __half2 p0 = __floats2half2_rn(v[0], v[1]);
            __half2 p1 = __floats2half2_rn(v[2], v[3]);
            __half2 p2 = __floats2half2_rn(v[4], v[5]);
            __half2 p3 = __floats2half2_rn(v[6], v[7]);
            uint4 pk4;
            pk4.x = *(unsigned*)&p0;
            pk4.y = *(unsigned*)&p1;
            pk4.z = *(unsigned*)&p2;
            pk4.w = *(unsigned*)&p3;
            *(uint4*)(xph + (size_t)g * 16 + cb) = pk4;
        }
    }
}

// Layer-1 aggregation launch A: phases {0,1}, q2 = bid&1. 8 lanes per node:
// qc = channel half (16B uint4 gathers), eh = edge quarter. 2-unrolled
// depth-1 pipeline; shfl_xor(2,4) combines quarters; eh==0 lanes nt-store
// partial[q2]. 32 nodes per block.
__global__ __launch_bounds__(256) void k_agg1(const int* __restrict__ rsg,
                                              const unsigned* __restrict__ spl,
                                              const unsigned* __restrict__ csr,
                                              const __half* __restrict__ xph,
                                              float* __restrict__ partial) {
    int t = threadIdx.x;
    int q2 = blockIdx.x & 1;
    int blk = blockIdx.x >> 1;
    int g = t >> 3;
    int h = t & 7;
    int qc = h & 1;
    int eh = h >> 1;
    int i = blk * 32 + g;
    unsigned sp = spl[i];
    int c0 = (int)(sp & 255u);
    int c1 = (int)((sp >> 8) & 255u);
    int beg = rsg[i] + (q2 ? c0 : 0);
    int end = beg + (q2 ? c1 : c0);

    float av[8];
#pragma unroll
    for (int c = 0; c < 8; ++c) av[c] = 0.0f;
    int j = beg + eh;
    int s0 = (j < end) ? (int)csr[j] : -1;
    int s1 = (j + 4 < end) ? (int)csr[j + 4] : -1;
    while (j < end) {
        int jn = j + 8;
        int n0 = (jn < end) ? (int)csr[jn] : -1;
        int n1 = (jn + 4 < end) ? (int)csr[jn + 4] : -1;
        uint4 u0 = *(const uint4*)(xph + (size_t)s0 * 16 + 8 * qc);
        acc8(av, u0);
        if (s1 >= 0) {
            uint4 u1 = *(const uint4*)(xph + (size_t)s1 * 16 + 8 * qc);
            acc8(av, u1);
        }
        s0 = n0;
        s1 = n1;
        j = jn;
    }
#pragma unroll
    for (int c = 0; c < 8; ++c) av[c] += __shfl_xor(av[c], 2);
#pragma unroll
    for (int c = 0; c < 8; ++c) av[c] += __shfl_xor(av[c], 4);
    if (eh == 0) {
        f4v r0 = {av[0], av[1], av[2], av[3]};
        f4v r1 = {av[4], av[5], av[6], av[7]};
        float* dst = partial + ((size_t)q2 * NN + i) * 16 + 8 * qc;
        __builtin_nontemporal_store(r0, (f4v*)dst);
        __builtin_nontemporal_store(r1, (f4v*)(dst + 4));
    }
}

// Launch B: phases {2,3} (contiguous csr range) + partial nt-read + self-loop
// + overflow fixup + fused MLP. 8 lanes per node (qc half x eh quarter);
// partials folded pre-combine (eh0: buf0+self, eh1: buf1); shfl_xor(2,4)
// sums; padded LDS tile exchanges agg; 2 hidden units per lane,
// shfl_xor(1,2,4) combines the output dot. Writes h2bp/selfout.
__global__ __launch_bounds__(256) void k_agg1m(const int* __restrict__ rsg,
                                               const unsigned* __restrict__ spl,
                                               const unsigned* __restrict__ csr,
                                               const __half* __restrict__ xph,
                                               const float* __restrict__ partial,
                                               const int* __restrict__ gcur,
                                               const ull* __restrict__ ovf,
                                               const float* __restrict__ dinv,
                                               const float* __restrict__ W1,
                                               const float* __restrict__ b1,
                                               const float* __restrict__ W2,
                                               const float* __restrict__ b2,
                                               float2* __restrict__ h2bp,
                                               float2* __restrict__ selfout) {
    __shared__ float sW1[IC * HC];
    __shared__ float sb1[HC];
    __shared__ float sW2[HC * OC];
    __shared__ float sb2[OC];
    __shared__ float sAgg[32][17];  // +1 pad: spread rows across banks
    int t = threadIdx.x;
    if (t < IC * HC) sW1[t] = W1[t];
    if (t < HC) sb1[t] = b1[t];
    if (t < HC * OC) sW2[t] = W2[t];
    if (t < OC) sb2[t] = b2[t];

    int g = t >> 3;
    int h = t & 7;
    int qc = h & 1;
    int eh = h >> 1;
    int i = blockIdx.x * 32 + g;   // NN = 6250*32 exactly
    unsigned sp = spl[i];
    int c0 = (int)(sp & 255u);
    int c1 = (int)((sp >> 8) & 255u);
    int c2 = (int)((sp >> 16) & 255u);
    int c3 = (int)(sp >> 24);
    int beg = rsg[i] + c0 + c1;    // phases 2+3 are contiguous
    int end = beg + c2 + c3;

    float av[8];
#pragma unroll
    for (int c = 0; c < 8; ++c) av[c] = 0.0f;
    int j = beg + eh;
    int s0 = (j < end) ? (int)csr[j] : -1;
    int s1 = (j + 4 < end) ? (int)csr[j + 4] : -1;
    while (j < end) {
        int jn = j + 8;
        int n0 = (jn < end) ? (int)csr[jn] : -1;
        int n1 = (jn + 4 < end) ? (int)csr[jn + 4] : -1;
        uint4 u0 = *(const uint4*)(xph + (size_t)s0 * 16 + 8 * qc);
        acc8(av, u0);
        if (s1 >= 0) {
            uint4 u1 = *(const uint4*)(xph + (size_t)s1 * 16 + 8 * qc);
            acc8(av, u1);
        }
        s0 = n0;
        s1 = n1;
        j = jn;
    }

    // fold partials/self pre-combine: eh0 -> buf0 + self row, eh1 -> buf1
    if (eh == 0) {
        const float* ps = partial + (size_t)i * 16 + 8 * qc;
        f4v p0 = __builtin_nontemporal_load((const f4v*)ps);
        f4v p1 = __builtin_nontemporal_load((const f4v*)(ps + 4));
        uint4 us = *(const uint4*)(xph + (size_t)i * 16 + 8 * qc);
        acc8(av, us);
        av[0] += p0.x; av[1] += p0.y; av[2] += p0.z; av[3] += p0.w;
        av[4] += p1.x; av[5] += p1.y; av[6] += p1.z; av[7] += p1.w;
    } else if (eh == 1) {
        const float* ps = partial + ((size_t)NN + i) * 16 + 8 * qc;
        f4v p0 = __builtin_nontemporal_load((const f4v*)ps);
        f4v p1 = __builtin_nontemporal_load((const f4v*)(ps + 4));
        av[0] += p0.x; av[1] += p0.y; av[2] += p0.z; av[3] += p0.w;
        av[4] += p1.x; av[5] += p1.y; av[6] += p1.z; av[7] += p1.w;
    }
#pragma unroll
    for (int c = 0; c < 8; ++c) av[c] += __shfl_xor(av[c], 2);
#pragma unroll
    for (int c = 0; c < 8; ++c) av[c] += __shfl_xor(av[c], 4);

    float dv = dinv[i];
    if (eh == 0) {
        // overflow fixup (nov==0 in practice)
        int nov = min(gcur[NSEG * GSTR], OVFCAP);
        for (int k = 0; k < nov; ++k) {
            ull e = ovf[k];
            if ((int)(e >> 32) == i) {
                int s = (int)(e & 0xFFFFFFFFu);
#pragma unroll
                for (int c = 0; c < 8; ++c)
                    av[c] += __half2float(xph[(size_t)s * 16 + 8 * qc + c]);
            }
        }
#pragma unroll
        for (int c = 0; c < 8; ++c) sAgg[g][8 * qc + c] = dv * av[c];
    }
    __syncthreads();

    // MLP: lane l8 = t&7 computes hidden units 2*l8, 2*l8+1 (sAgg row is an
    // LDS broadcast across the node's 8 lanes).
    int l8 = t & 7;
    float o0 = 0.0f, o1 = 0.0f;
#pragma unroll
    for (int f2 = 0; f2 < 2; ++f2) {
        int f = 2 * l8 + f2;
        float a = sb1[f];
#pragma unroll
        for (int c = 0; c < IC; ++c) a = fmaf(sAgg[g][c], sW1[c * HC + f], a);
        a = fmaxf(a, 0.0f);
        o0 = fmaf(a, sW2[f * OC + 0], o0);
        o1 = fmaf(a, sW2[f * OC + 1], o1);
    }
    o0 += __shfl_xor(o0, 1);
    o1 += __shfl_xor(o1, 1);
    o0 += __shfl_xor(o0, 2);
    o1 += __shfl_xor(o1, 2);
    o0 += __shfl_xor(o0, 4);
    o1 += __shfl_xor(o1, 4);
    if (l8 == 0) {
        h2bp[i] = make_float2(o0 * dv, o1 * dv);  // dinv-prescaled for layer 2
        selfout[i] = make_float2(o0 * dv * dv + sb2[0], o1 * dv * dv + sb2[1]);
    }
}

// layer-2: out[i] = selfout[i] + dinv[i] * (sum h2bp[src] + ovf matches).
// 8 lanes per node, depth-1 csr pipeline; shfl_xor(1,2,4) combine.
__global__ __launch_bounds__(256) void k_agg2(const int* __restrict__ rsg,
                                              const unsigned* __restrict__ spl,
                                              const unsigned* __restrict__ csr,
                                              const int* __restrict__ gcur,
                                              const ull* __restrict__ ovf,
                                              const float* __restrict__ dinv,
                                              const float2* __restrict__ h2bp,
                                              const float2* __restrict__ selfout,
                                              float2* __restrict__ out) {
    int tt = blockIdx.x * 256 + threadIdx.x;
    int i = tt >> 3;
    int h = tt & 7;
    if (i >= NN) return;
    unsigned sp = spl[i];
    int tot = (int)(sp & 255u) + (int)((sp >> 8) & 255u) +
              (int)((sp >> 16) & 255u) + (int)(sp >> 24);
    int beg = rsg[i];
    int end = beg + tot;
    float ax = 0.0f, ay = 0.0f;
    int j = beg + h;
    int s0 = (j < end) ? (int)csr[j] : -1;
    int s1 = (j + 8 < end) ? (int)csr[j + 8] : -1;
    while (j < end) {
        int jn = j + 16;
        int n0 = (jn < end) ? (int)csr[jn] : -1;
        int n1 = (jn + 8 < end) ? (int)csr[jn + 8] : -1;
        float2 h0 = h2bp[s0];
        ax += h0.x;
        ay += h0.y;
        if (s1 >= 0) {
            float2 h1 = h2bp[s1];
            ax += h1.x;
            ay += h1.y;
        }
        s0 = n0;
        s1 = n1;
        j = jn;
    }
    ax += __shfl_xor(ax, 1);
    ay += __shfl_xor(ay, 1);
    ax += __shfl_xor(ax, 2);
    ay += __shfl_xor(ay, 2);
    ax += __shfl_xor(ax, 4);
    ay += __shfl_xor(ay, 4);
    if (h == 0) {
        // overflow fixup (nov==0 in practice); h2bp already dinv[src]-prescaled
        int nov = min(gcur[NSEG * GSTR], OVFCAP);
        for (int k = 0; k < nov; ++k) {
            ull e = ovf[k];
            if ((int)(e >> 32) == i) {
                float2 hh = h2bp[(int)(e & 0xFFFFFFFFu)];
                ax += hh.x;
                ay += hh.y;
            }
        }
        float dv = dinv[i];
        float2 so = selfout[i];
        out[i] = make_float2(so.x + dv * ax, so.y + dv * ay);
    }
}

extern "C" void kernel_launch(void* const* d_in, const int* in_sizes, int n_in,
                              void* d_out, int out_size, void* d_ws, size_t ws_size,
                              hipStream_t stream) {
    const float* x = (const float*)d_in[0];
    const void* ei = d_in[1];
    // d_in[2] = edge_attr (unused)
    const float* W1 = (const float*)d_in[3];
    const float* b1 = (const float*)d_in[4];
    const float* W2 = (const float*)d_in[5];
    const float* b2 = (const float*)d_in[6];
    float* out = (float*)d_out;

    ull* ovf = (ull*)d_ws;                              // OVFCAP       (0.5MB)
    int* gcur = (int*)(ovf + OVFCAP);                   // (NSEG+5)*16 ints
    int* flag = gcur + (NSEG + 5) * GSTR;               // 4
    int* rsg = flag + 4;                                // NN
    unsigned* spl = (unsigned*)(rsg + NN);              // NN
    float* dinv = (float*)(spl + NN);                   // NN
    __half* xph = (__half*)(dinv + NN);                 // NN*16 halves (6.4MB)
    float2* h2bp = (float2*)(xph + (size_t)NN * 16);    // NN
    float2* selfout = h2bp + NN;                        // NN
    unsigned* binned = (unsigned*)(selfout + NN);       // NSEG*SCAP    (35.3MB)
    float* partial = (float*)binned;                    // 2*NN*16 f32 (25.6MB), overlays
                                                        // binned (dead after k_sort)
    unsigned* csr = binned + (size_t)NSEG * SCAP;       // NBK*CCAP     (35.3MB)

    k_init<<<(NSEG + 5 + 255) / 256, 256, 0, stream>>>(gcur, ei, flag);
    k_binA<<<NTILE, BTH, 0, stream>>>(ei, flag, gcur, binned, ovf);
    k_sort<<<NBK, 1024, 0, stream>>>(gcur, binned, ovf, x, csr, dinv, rsg, spl, xph);
    k_agg1<<<2 * NM, 256, 0, stream>>>(rsg, spl, csr, xph, partial);
    k_agg1m<<<NM, 256, 0, stream>>>(rsg, spl, csr, xph, partial, gcur, ovf, dinv,
                                    W1, b1, W2, b2, h2bp, selfout);
    k_agg2<<<(NN * 8 + 255) / 256, 256, 0, stream>>>(rsg, spl, csr, gcur, ovf, dinv,
                                                     h2bp, selfout, (float2*)out);
}

// Round 12
// 270.313 us; speedup vs baseline: 1.3102x; 1.0047x over previous
//
#include <hip/hip_runtime.h>
#include <hip/hip_fp16.h>

// GCN 2-layer: N=200000, E=6400000, 14 -> 16(relu) -> 2.
// Round 24: delete the partial round-trip. agg1m's FETCH decomposed as
// csr 12.8 + PARTIAL READ 25.6 + self 6.4 + refetch ~7MB -- the gathers are
// cache-resident now; the 2-launch phase split's partial buffer (25.6MB
// write + 25.6MB read + one launch) is the biggest remaining traffic item.
// csr rows are phase-sorted per node and degrees are tight (mean 32,
// sigma~5.7), so co-resident blocks walking FULL rows traverse the four
// 1.6MB xph phase regions approximately in lockstep -> live gather set
// ~2 regions < 4MB L2, no partial needed.
//   - k_agg1f = full-row gather + self + ovf + fused MLP (one launch).
//   - agg1A + partial buffer deleted.
// Pipeline: init -> binA -> sort(+dinv+xph) -> agg1f -> agg2.

constexpr int NN = 200000;
constexpr int NE = 6400000;
constexpr int IC = 14;
constexpr int HC = 16;
constexpr int OC = 2;

constexpr int NBK = 392;                   // buckets of 512 dst nodes
constexpr int NSUB = 8;                    // sub-segments per bucket (= XCD id)
constexpr int SCAP = 2816;                 // per (sub,bucket) cap: mean 2058 + 16.7 sigma
constexpr int NSEG = NSUB * NBK;           // 3136 segments
constexpr int CCAP = NSUB * SCAP;          // 22528 csr per-bucket capacity
constexpr int SPT = (SCAP + 1023) / 1024;  // 3 reg slots per (thread, segment)
constexpr int TILE = 5120;                 // edges per binA tile
constexpr int BTH = 512;                   // binA threads
constexpr int IPT = TILE / BTH;            // 10
constexpr int IPT2 = IPT / 2;              // 5 pair-loads per thread
constexpr int NTILE = NE / TILE;           // 1250
constexpr int OVFCAP = 65536;
constexpr int NM = NN / 32;                // 6250 blocks (32 nodes per block)
constexpr int GSTR = 16;                   // gcur stride: 1 counter per 64B line

typedef unsigned long long ull;
typedef float f4v __attribute__((ext_vector_type(4)));

__device__ __forceinline__ int phase_of(unsigned src) {
    return src >= 100000u ? (src >= 150000u ? 3 : 2) : (src >= 50000u ? 1 : 0);
}

// Physical XCD id (0..7). Affinity heuristic only -- correctness never
// depends on the value (G16): binA has the overflow path.
__device__ __forceinline__ int xcc_id() {
    int x;
    asm volatile("s_getreg_b32 %0, hwreg(HW_REG_XCC_ID)" : "=s"(x));
    return x & 7;
}

// accumulate 8 halves (one 16B xph half-row) into av[8]
__device__ __forceinline__ void acc8(float* av, uint4 u) {
    float2 f0 = __half22float2(*(__half2*)&u.x);
    float2 f1 = __half22float2(*(__half2*)&u.y);
    float2 f2 = __half22float2(*(__half2*)&u.z);
    float2 f3 = __half22float2(*(__half2*)&u.w);
    av[0] += f0.x; av[1] += f0.y; av[2] += f1.x; av[3] += f1.y;
    av[4] += f2.x; av[5] += f2.y; av[6] += f3.x; av[7] += f3.y;
}

// init gcur (padded) + ovf counter + dtype flag
__global__ void k_init(int* __restrict__ gcur, const void* __restrict__ ei,
                       int* __restrict__ flag) {
    int i = blockIdx.x * blockDim.x + threadIdx.x;
    if (i < NSEG) gcur[i * GSTR] = i * SCAP;
    else if (i <= NSEG + 4) gcur[i * GSTR] = 0;  // ovf counter (+spare)
    if (i == 500) {  // one thread sniffs edge dtype
        const ull* p = (const ull*)ei;
        ull acc = 0ULL;
        for (int k = 0; k < 64; ++k) acc |= (p[k] >> 32);
        *flag = (acc == 0ULL) ? 1 : 0;  // 1 => int64 indices, 0 => int32
    }
}

// Bin edges by dst>>9 into per-(sub,bucket) global segments, sub = XCC_ID.
// All edge words preloaded to registers (20 independent loads in flight),
// then the atomic/pack loop runs against warm registers. LDS-staged for
// coalesced segment write-out.
__global__ __launch_bounds__(BTH, 6) void k_binA(const void* __restrict__ ei,
                                                 const int* __restrict__ flag,
                                                 int* __restrict__ gcur,
                                                 unsigned* __restrict__ binned,
                                                 ull* __restrict__ ovf) {
    __shared__ int hist[NBK];
    __shared__ int lofs[NBK];
    __shared__ int gofs[NBK];
    __shared__ int wsum[BTH / 64];
    __shared__ unsigned stage[TILE];

    int t = threadIdx.x;
    int fl = *flag;
    int tile0 = blockIdx.x * TILE;
    int segbase = xcc_id() * NBK;

    if (t < NBK) hist[t] = 0;
    __syncthreads();

    // preload: 20 independent dword loads (int64 path reads low dwords only)
    int dbuf[IPT], sbuf[IPT];
    const int* pw = (const int*)ei;
    if (fl) {
#pragma unroll
        for (int k = 0; k < IPT2; ++k) {
            int e = tile0 + k * (2 * BTH) + 2 * t;
            dbuf[2 * k] = pw[2 * (NE + e)];
            dbuf[2 * k + 1] = pw[2 * (NE + e) + 2];
            sbuf[2 * k] = pw[2 * e];
            sbuf[2 * k + 1] = pw[2 * e + 2];
        }
    } else {
#pragma unroll
        for (int k = 0; k < IPT2; ++k) {
            int e = tile0 + k * (2 * BTH) + 2 * t;
            uint2 dd = *(const uint2*)(pw + NE + e);
            uint2 ss = *(const uint2*)(pw + e);
            dbuf[2 * k] = (int)dd.x;
            dbuf[2 * k + 1] = (int)dd.y;
            sbuf[2 * k] = (int)ss.x;
            sbuf[2 * k + 1] = (int)ss.y;
        }
    }

    // atomic rank capture from registers.
    // pk = (dlow<<18)|src ; ra = (rank<<9)|bucket  (rank<5120 fits 13 bits)
    unsigned pk[IPT];
    unsigned ra[IPT];
#pragma unroll
    for (int k = 0; k < IPT; ++k) {
        int d = dbuf[k];
        int b = d >> 9;
        int r = atomicAdd(&hist[b], 1);
        pk[k] = ((unsigned)(d & 511) << 18) | (unsigned)sbuf[k];
        ra[k] = ((unsigned)r << 9) | (unsigned)b;
    }
    __syncthreads();

    // exclusive scan of 392 counts: pair-sum + 64-lane shfl scan + wave combine
    int h0 = 0, h1 = 0, p = 0;
    if (t < NBK / 2) {
        h0 = hist[2 * t];
        h1 = hist[2 * t + 1];
        p = h0 + h1;
    }
    int lane = t & 63;
    int w = t >> 6;
    int incl = p;
#pragma unroll
    for (int off = 1; off < 64; off <<= 1) {
        int v = __shfl_up(incl, off, 64);
        if (lane >= off) incl += v;
    }
    if (lane == 63) wsum[w] = incl;
    __syncthreads();
    int wbase = 0;
#pragma unroll
    for (int ww = 0; ww < BTH / 64; ++ww) wbase += (ww < w) ? wsum[ww] : 0;
    int ex = wbase + incl - p;
    if (t < NBK / 2) {
        lofs[2 * t] = ex;
        lofs[2 * t + 1] = ex + h0;
    }
    if (t < NBK) gofs[t] = atomicAdd(&gcur[(segbase + t) * GSTR], hist[t]);
    __syncthreads();

    // stage from regs at lofs[bucket] + rank (no global loads)
#pragma unroll
    for (int k = 0; k < IPT; ++k) {
        int b = (int)(ra[k] & 511u);
        int r = (int)(ra[k] >> 9);
        stage[lofs[b] + r] = pk[k];
    }
    __syncthreads();

    // coalesced write-out; bucket of slot i via seeded search on lofs
    for (int i = t; i < TILE; i += BTH) {
        int b = (i * 313) >> 12;  // ~ i / 13.06 (mean slots per bucket)
        if (b > NBK - 1) b = NBK - 1;
        while (b < NBK - 1 && lofs[b + 1] <= i) ++b;
        while (lofs[b] > i) --b;
        unsigned pack = stage[i];
        int seg = segbase + b;
        int dest = gofs[b] + (i - lofs[b]);
        if (dest < (seg + 1) * SCAP) {
            binned[dest] = pack;
        } else {  // overflow (never in practice)
            int op = atomicAdd(&gcur[NSEG * GSTR], 1);
            if (op < OVFCAP) {
                int d = (b << 9) | (int)(pack >> 18);
                int s = (int)(pack & 0x3FFFF);
                ovf[op] = ((ull)d << 32) | (unsigned)s;
            }
        }
    }
}

// bucket-local counting sort over 8 sub-segments, key = (dlow<<2)|phase(src).
// Single pass: rank captured from cnt atomic, (src, rank|key) in regs;
// scatter into LDS stage; coalesced uint4 write-out. Computes dinv and packed
// phase counts. Fused prep: after write-out, 2 threads/node write the
// block's 512 xph rows (fp16 dinv*x, padded to 16 halves).
__global__ __launch_bounds__(1024, 4) void k_sort(const int* __restrict__ gcur,
                                                  const unsigned* __restrict__ binned,
                                                  const ull* __restrict__ ovf,
                                                  const float* __restrict__ x,
                                                  unsigned* __restrict__ csr,
                                                  float* __restrict__ dinv,
                                                  int* __restrict__ rsg,
                                                  unsigned* __restrict__ spl,
                                                  __half* __restrict__ xph) {
    __shared__ int cnt[2048];
    __shared__ int excl[2048];
    __shared__ int wsum[16];
    __shared__ int nseg[NSUB];
    __shared__ float sdv[512];
    __shared__ unsigned stage[CCAP];      // 88KB sorted bucket staging
    int b = blockIdx.x;
    int t = threadIdx.x;
    cnt[t] = 0;
    cnt[t + 1024] = 0;
    if (t < NSUB) {
        int seg = t * NBK + b;
        nseg[t] = min(gcur[seg * GSTR] - seg * SCAP, SCAP);
    }
    __syncthreads();
    int nov = min(gcur[NSEG * GSTR], OVFCAP);

    // single pass: load + key + rank capture; held in regs (static indexing)
    unsigned srcv[NSUB * SPT];
    unsigned rkv[NSUB * SPT];
#pragma unroll
    for (int s = 0; s < NSUB; ++s) {
        int n = nseg[s];
        int sb = (s * NBK + b) * SCAP;
#pragma unroll
        for (int k = 0; k < SPT; ++k) {
            int i = k * 1024 + t;
            rkv[s * SPT + k] = 0xFFFFFFFFu;
            if (i < n) {
                unsigned pack = binned[sb + i];
                unsigned src = pack & 0x3FFFFu;
                int key = ((int)(pack >> 18) << 2) | phase_of(src);
                int r = atomicAdd(&cnt[key], 1);
                srcv[s * SPT + k] = src;
                rkv[s * SPT + k] = ((unsigned)r << 11) | (unsigned)key;
            }
        }
    }
    __syncthreads();

    // exclusive scan of 2048 counts: pair-sum + 1024-lane scan (16 waves)
    int h0 = cnt[2 * t];
    int h1 = cnt[2 * t + 1];
    int p = h0 + h1;
    int lane = t & 63;
    int w = t >> 6;
    int incl = p;
#pragma unroll
    for (int off = 1; off < 64; off <<= 1) {
        int v = __shfl_up(incl, off, 64);
        if (lane >= off) incl += v;
    }
    if (lane == 63) wsum[w] = incl;
    __syncthreads();
    int wbase = 0;
#pragma unroll
    for (int ww = 0; ww < 16; ++ww) wbase += (ww < w) ? wsum[ww] : 0;
    int ex = wbase + incl - p;
    excl[2 * t] = ex;
    excl[2 * t + 1] = ex + h0;
    __syncthreads();

    // scatter into LDS stage (bucket-relative positions)
#pragma unroll
    for (int c = 0; c < NSUB * SPT; ++c) {
        unsigned rk = rkv[c];
        if (rk != 0xFFFFFFFFu) {
            int key = (int)(rk & 0x7FFu);
            int r = (int)(rk >> 11);
            stage[excl[key] + r] = srcv[c];
        }
    }

    // per-node stats (cnt/excl are stable; independent of stage)
    if (t < 512) {
        int g = (b << 9) + t;
        if (g < NN) {
            int c0 = cnt[4 * t];
            int c1 = cnt[4 * t + 1];
            int c2 = cnt[4 * t + 2];
            int c3 = cnt[4 * t + 3];
            int extra = 0;
            for (int k = 0; k < nov; ++k) extra += ((int)(ovf[k] >> 32) == g);
            float dv = rsqrtf((float)(c0 + c1 + c2 + c3 + extra) + 1.0f);
            dinv[g] = dv;
            sdv[t] = dv;
            rsg[g] = b * CCAP + excl[4 * t];                 // csr row start (absolute)
            spl[g] = (unsigned)c0 | ((unsigned)c1 << 8) |
                     ((unsigned)c2 << 16) | ((unsigned)c3 << 24);
        }
    }
    __syncthreads();

    // coalesced uint4 write-out (pad to 16B; garbage pad stays in-bucket)
    int total = excl[2047] + cnt[2047];
    int tot4 = (total + 3) >> 2;
    const uint4* st4 = (const uint4*)stage;
    uint4* csr4 = (uint4*)(csr + (size_t)b * CCAP);
#pragma unroll
    for (int k = 0; k < (CCAP / 4 + 1023) / 1024; ++k) {
        int i4 = k * 1024 + t;
        if (i4 < tot4) csr4[i4] = st4[i4];
    }

    // fused prep: xph rows for this block's 512 nodes (2 threads per node,
    // 8 halves each). sdv synced by the pre-write-out barrier.
    {
        int n512 = t >> 1;
        int g = (b << 9) + n512;
        if (g < NN) {
            float dv = sdv[n512];
            int cb = 8 * (t & 1);
            const float* xr = x + (size_t)g * IC;
            float v[8];
#pragma unroll
            for (int c = 0; c < 8; c += 2) {
                int ch = cb + c;
                if (ch + 1 < IC) {
                    float2 xx = *(const float2*)(xr + ch);
                    v[c] = dv * xx.x;
                    v[c + 1] = dv * xx.y;
                } else {
                    v[c] = 0.0f;
                    v[c + 1] = 0.0f;
                }
            }
            __half2 p0 = __floats2half2_rn(v[0], v[1]);
            __half2 p1 = __floats2half2_rn(v[2], v[3]);
            __half2 p2 = __floats2half2_rn(v[4], v[5]);
            __half2 p3 = __floats2half2_rn(v[6], v[7]);
            uint4 pk4;
            pk4.x = *(unsigned*)&p0;
            pk4.y = *(unsigned*)&p1;
            pk4.z = *(unsigned*)&p2;
            pk4.w = *(unsigned*)&p3;
            *(uint4*)(xph + (size_t)g * 16 + cb) = pk4;
        }
    }
}

// Fused layer-1: FULL csr row gather (phase-sorted -> co-resident blocks
// traverse the 1.6MB phase regions ~in lockstep, live set < L2) + self row
// + overflow fixup + fused MLP. 8 lanes per node (qc channel half x eh edge
// quarter, 16B uint4 gathers); shfl_xor(2,4) sums; padded LDS tile exchanges
// agg; 2 hidden units per lane, shfl_xor(1,2,4) combines the output dot.
// Writes only h2bp/selfout (3.2MB). No partial buffer.
__global__ __launch_bounds__(256) void k_agg1f(const int* __restrict__ rsg,
                                               const unsigned* __restrict__ spl,
                                               const unsigned* __restrict__ csr,
                                               const __half* __restrict__ xph,
                                               const int* __restrict__ gcur,
                                               const ull* __restrict__ ovf,
                                               const float* __restrict__ dinv,
                                               const float* __restrict__ W1,
                                               const float* __restrict__ b1,
                                               const float* __restrict__ W2,
                                               const float* __restrict__ b2,
                                               float2* __restrict__ h2bp,
                                               float2* __restrict__ selfout) {
    __shared__ float sW1[IC * HC];
    __shared__ float sb1[HC];
    __shared__ float sW2[HC * OC];
    __shared__ float sb2[OC];
    __shared__ float sAgg[32][17];  // +1 pad: spread rows across banks
    int t = threadIdx.x;
    if (t < IC * HC) sW1[t] = W1[t];
    if (t < HC) sb1[t] = b1[t];
    if (t < HC * OC) sW2[t] = W2[t];
    if (t < OC) sb2[t] = b2[t];

    int g = t >> 3;
    int h = t & 7;
    int qc = h & 1;
    int eh = h >> 1;
    int i = blockIdx.x * 32 + g;   // NN = 6250*32 exactly
    unsigned sp = spl[i];
    int tot = (int)(sp & 255u) + (int)((sp >> 8) & 255u) +
              (int)((sp >> 16) & 255u) + (int)(sp >> 24);
    int beg = rsg[i];
    int end = beg + tot;

    float av[8];
#pragma unroll
    for (int c = 0; c < 8; ++c) av[c] = 0.0f;
    int j = beg + eh;
    int s0 = (j < end) ? (int)csr[j] : -1;
    int s1 = (j + 4 < end) ? (int)csr[j + 4] : -1;
    while (j < end) {
        int jn = j + 8;
        int n0 = (jn < end) ? (int)csr[jn] : -1;
        int n1 = (jn + 4 < end) ? (int)csr[jn + 4] : -1;
        uint4 u0 = *(const uint4*)(xph + (size_t)s0 * 16 + 8 * qc);
        acc8(av, u0);
        if (s1 >= 0) {
            uint4 u1 = *(const uint4*)(xph + (size_t)s1 * 16 + 8 * qc);
            acc8(av, u1);
        }
        s0 = n0;
        s1 = n1;
        j = jn;
    }

    // self row folded pre-combine by eh==0 lanes (once per qc half)
    if (eh == 0) {
        uint4 us = *(const uint4*)(xph + (size_t)i * 16 + 8 * qc);
        acc8(av, us);
    }
#pragma unroll
    for (int c = 0; c < 8; ++c) av[c] += __shfl_xor(av[c], 2);
#pragma unroll
    for (int c = 0; c < 8; ++c) av[c] += __shfl_xor(av[c], 4);

    float dv = dinv[i];
    if (eh == 0) {
        // overflow fixup (nov==0 in practice)
        int nov = min(gcur[NSEG * GSTR], OVFCAP);
        for (int k = 0; k < nov; ++k) {
            ull e = ovf[k];
            if ((int)(e >> 32) == i) {
                int s = (int)(e & 0xFFFFFFFFu);
#pragma unroll
                for (int c = 0; c < 8; ++c)
                    av[c] += __half2float(xph[(size_t)s * 16 + 8 * qc + c]);
            }
        }
#pragma unroll
        for (int c = 0; c < 8; ++c) sAgg[g][8 * qc + c] = dv * av[c];
    }
    __syncthreads();

    // MLP: lane l8 = t&7 computes hidden units 2*l8, 2*l8+1 (sAgg row is an
    // LDS broadcast across the node's 8 lanes).
    int l8 = t & 7;
    float o0 = 0.0f, o1 = 0.0f;
#pragma unroll
    for (int f2 = 0; f2 < 2; ++f2) {
        int f = 2 * l8 + f2;
        float a = sb1[f];
#pragma unroll
        for (int c = 0; c < IC; ++c) a = fmaf(sAgg[g][c], sW1[c * HC + f], a);
        a = fmaxf(a, 0.0f);
        o0 = fmaf(a, sW2[f * OC + 0], o0);
        o1 = fmaf(a, sW2[f * OC + 1], o1);
    }
    o0 += __shfl_xor(o0, 1);
    o1 += __shfl_xor(o1, 1);
    o0 += __shfl_xor(o0, 2);
    o1 += __shfl_xor(o1, 2);
    o0 += __shfl_xor(o0, 4);
    o1 += __shfl_xor(o1, 4);
    if (l8 == 0) {
        h2bp[i] = make_float2(o0 * dv, o1 * dv);  // dinv-prescaled for layer 2
        selfout[i] = make_float2(o0 * dv * dv + sb2[0], o1 * dv * dv + sb2[1]);
    }
}

// layer-2: out[i] = selfout[i] + dinv[i] * (sum h2bp[src] + ovf matches).
// 8 lanes per node, depth-1 csr pipeline; shfl_xor(1,2,4) combine.
__global__ __launch_bounds__(256) void k_agg2(const int* __restrict__ rsg,
                                              const unsigned* __restrict__ spl,
                                              const unsigned* __restrict__ csr,
                                              const int* __restrict__ gcur,
                                              const ull* __restrict__ ovf,
                                              const float* __restrict__ dinv,
                                              const float2* __restrict__ h2bp,
                                              const float2* __restrict__ selfout,
                                              float2* __restrict__ out) {
    int tt = blockIdx.x * 256 + threadIdx.x;
    int i = tt >> 3;
    int h = tt & 7;
    if (i >= NN) return;
    unsigned sp = spl[i];
    int tot = (int)(sp & 255u) + (int)((sp >> 8) & 255u) +
              (int)((sp >> 16) & 255u) + (int)(sp >> 24);
    int beg = rsg[i];
    int end = beg + tot;
    float ax = 0.0f, ay = 0.0f;
    int j = beg + h;
    int s0 = (j < end) ? (int)csr[j] : -1;
    int s1 = (j + 8 < end) ? (int)csr[j + 8] : -1;
    while (j < end) {
        int jn = j + 16;
        int n0 = (jn < end) ? (int)csr[jn] : -1;
        int n1 = (jn + 8 < end) ? (int)csr[jn + 8] : -1;
        float2 h0 = h2bp[s0];
        ax += h0.x;
        ay += h0.y;
        if (s1 >= 0) {
            float2 h1 = h2bp[s1];
            ax += h1.x;
            ay += h1.y;
        }
        s0 = n0;
        s1 = n1;
        j = jn;
    }
    ax += __shfl_xor(ax, 1);
    ay += __shfl_xor(ay, 1);
    ax += __shfl_xor(ax, 2);
    ay += __shfl_xor(ay, 2);
    ax += __shfl_xor(ax, 4);
    ay += __shfl_xor(ay, 4);
    if (h == 0) {
        // overflow fixup (nov==0 in practice); h2bp already dinv[src]-prescaled
        int nov = min(gcur[NSEG * GSTR], OVFCAP);
        for (int k = 0; k < nov; ++k) {
            ull e = ovf[k];
            if ((int)(e >> 32) == i) {
                float2 hh = h2bp[(int)(e & 0xFFFFFFFFu)];
                ax += hh.x;
                ay += hh.y;
            }
        }
        float dv = dinv[i];
        float2 so = selfout[i];
        out[i] = make_float2(so.x + dv * ax, so.y + dv * ay);
    }
}

extern "C" void kernel_launch(void* const* d_in, const int* in_sizes, int n_in,
                              void* d_out, int out_size, void* d_ws, size_t ws_size,
                              hipStream_t stream) {
    const float* x = (const float*)d_in[0];
    const void* ei = d_in[1];
    // d_in[2] = edge_attr (unused)
    const float* W1 = (const float*)d_in[3];
    const float* b1 = (const float*)d_in[4];
    const float* W2 = (const float*)d_in[5];
    const float* b2 = (const float*)d_in[6];
    float* out = (float*)d_out;

    ull* ovf = (ull*)d_ws;                              // OVFCAP       (0.5MB)
    int* gcur = (int*)(ovf + OVFCAP);                   // (NSEG+5)*16 ints
    int* flag = gcur + (NSEG + 5) * GSTR;               // 4
    int* rsg = flag + 4;                                // NN
    unsigned* spl = (unsigned*)(rsg + NN);              // NN
    float* dinv = (float*)(spl + NN);                   // NN
    __half* xph = (__half*)(dinv + NN);                 // NN*16 halves (6.4MB)
    float2* h2bp = (float2*)(xph + (size_t)NN * 16);    // NN
    float2* selfout = h2bp + NN;                        // NN
    unsigned* binned = (unsigned*)(selfout + NN);       // NSEG*SCAP    (35.3MB)
    unsigned* csr = binned + (size_t)NSEG * SCAP;       // NBK*CCAP     (35.3MB)

    k_init<<<(NSEG + 5 + 255) / 256, 256, 0, stream>>>(gcur, ei, flag);
    k_binA<<<NTILE, BTH, 0, stream>>>(ei, flag, gcur, binned, ovf);
    k_sort<<<NBK, 1024, 0, stream>>>(gcur, binned, ovf, x, csr, dinv, rsg, spl, xph);
    k_agg1f<<<NM, 256, 0, stream>>>(rsg, spl, csr, xph, gcur, ovf, dinv,
                                    W1, b1, W2, b2, h2bp, selfout);
    k_agg2<<<(NN * 8 + 255) / 256, 256, 0, stream>>>(rsg, spl, csr, gcur, ovf, dinv,
                                                     h2bp, selfout, (float2*)out);
}